// Round 4
// baseline (1264.350 us; speedup 1.0000x reference)
//
#include <hip/hip_runtime.h>
#include <math.h>

// Problem constants (fixed by the reference).
#define N_NODES 50000
#define N_EDGES 640000   // divisible by 32 (20000 tiles) and 256
#define NLAYER  4
#define NPAD    50016    // N_NODES rounded up to 32

typedef unsigned short bf16_t;
typedef __attribute__((ext_vector_type(8))) short s16x8;   // 8 bf16 = 4 VGPR (MFMA A/B frag)
typedef __attribute__((ext_vector_type(4))) float f32x4;   // MFMA C/D frag

__device__ __forceinline__ float gelu_f(float x) {
    return 0.5f * x * (1.0f + tanhf(0.7978845608028654f * (x + 0.044715f * x * x * x)));
}

__device__ __forceinline__ bf16_t f2bf(float f) {
    unsigned u = __float_as_uint(f);
    unsigned r = (u + 0x7FFFu + ((u >> 16) & 1u)) >> 16;   // RNE
    return (bf16_t)r;
}
__device__ __forceinline__ float bf2f(bf16_t h) { return __uint_as_float(((unsigned)h) << 16); }
__device__ __forceinline__ float bfl(unsigned x) { return __uint_as_float(x << 16); }
__device__ __forceinline__ float bfh(unsigned x) { return __uint_as_float(x & 0xFFFF0000u); }

// ---------------- CSR build (counting sort by dst) ----------------
__global__ void k_zero32(unsigned* p, int n) {
    int i = blockIdx.x * 256 + threadIdx.x;
    if (i < n) p[i] = 0u;
}

__global__ void k_hist(const int* __restrict__ dst, int* __restrict__ deg) {
    int i = blockIdx.x * 256 + threadIdx.x;
    if (i < N_EDGES) atomicAdd(&deg[dst[i]], 1);
}

__global__ void k_scan1(const int* __restrict__ deg, int* __restrict__ rowptr, int* __restrict__ bsum) {
    __shared__ int sd[1024];
    int gi = blockIdx.x * 1024 + threadIdx.x;
    int v = (gi < N_NODES) ? deg[gi] : 0;
    sd[threadIdx.x] = v;
    __syncthreads();
    for (int off = 1; off < 1024; off <<= 1) {
        int t2 = (threadIdx.x >= (unsigned)off) ? sd[threadIdx.x - off] : 0;
        __syncthreads();
        sd[threadIdx.x] += t2;
        __syncthreads();
    }
    if (gi < N_NODES) rowptr[gi] = sd[threadIdx.x] - v;  // block-local exclusive
    if (threadIdx.x == 1023) bsum[blockIdx.x] = sd[1023];
}

__global__ void k_scan2(const int* __restrict__ bsum, int* __restrict__ boff, int nb) {
    if (threadIdx.x == 0 && blockIdx.x == 0) {
        int run = 0;
        for (int b = 0; b < nb; b++) { boff[b] = run; run += bsum[b]; }
    }
}

__global__ void k_scan3(int* __restrict__ rowptr, const int* __restrict__ boff) {
    int gi = blockIdx.x * 1024 + threadIdx.x;
    if (gi < N_NODES) rowptr[gi] += boff[blockIdx.x];
    if (gi == 0) rowptr[N_NODES] = N_EDGES;
}

__global__ void k_copy(const int* __restrict__ a, int* __restrict__ b) {
    int i = blockIdx.x * 256 + threadIdx.x;
    if (i < N_NODES) b[i] = a[i];
}

__global__ void k_scatter(const int* __restrict__ dst, int* __restrict__ cursor, int* __restrict__ eidx) {
    int i = blockIdx.x * 256 + threadIdx.x;
    if (i < N_EDGES) {
        int p = atomicAdd(&cursor[dst[i]], 1);
        eidx[p] = i;
    }
}

// Gather per-edge fields into dst-sorted order, compact 24 B/edge:
// emA[i] = { src, dst, combo = etype*9+erid, rc0|rc1<<16 (bf16) }
// emB[i] = { rp0|rp1<<16 (bf16), rp2 (bf16) }
__global__ void k_sortgather(
    const int* __restrict__ eidx, const int* __restrict__ src, const int* __restrict__ dst,
    const int* __restrict__ etype, const int* __restrict__ erid,
    const float* __restrict__ att_rc, const float* __restrict__ att_rp,
    int* __restrict__ src_s, uint4* __restrict__ emA, uint2* __restrict__ emB)
{
    int i = blockIdx.x * 256 + threadIdx.x;
    if (i < N_EDGES) {
        int e = eidx[i];
        int sv = src[e];
        src_s[i] = sv;
        uint4 a;
        a.x = (unsigned)sv;
        a.y = (unsigned)dst[e];
        a.z = (unsigned)(etype[e] * 9 + erid[e]);
        a.w = (unsigned)f2bf(att_rc[2 * e]) | ((unsigned)f2bf(att_rc[2 * e + 1]) << 16);
        uint2 b;
        b.x = (unsigned)f2bf(att_rp[3 * e]) | ((unsigned)f2bf(att_rp[3 * e + 1]) << 16);
        b.y = (unsigned)f2bf(att_rp[3 * e + 2]);
        emA[i] = a;
        emB[i] = b;
    }
}

// ---------------- (etype,erid)-combo base table: 315 x 64 fp32 (~80 KB, cache-hot) ----------
__global__ void k_base(const float* __restrict__ type_emb, const float* __restrict__ rid_emb,
                       const float* __restrict__ rcb, const float* __restrict__ rpb,
                       float* __restrict__ base)
{
    int idx = blockIdx.x * 256 + threadIdx.x;
    if (idx >= 315 * 64) return;
    int c = idx >> 6, k = idx & 63;
    int et = c / 9, er = c % 9;
    base[idx] = type_emb[et * 64 + k] + rid_emb[er * 64 + k] + rcb[k] + rpb[k];
}

// Weight transposes to bf16, k-contiguous rows (MFMA A-operand friendly).
__global__ void k_wprep(const float* __restrict__ Wfij, const float* __restrict__ Wni,
                        const float* __restrict__ Wnj, const float* __restrict__ Wnode,
                        const float* __restrict__ W1, const float* __restrict__ W2,
                        bf16_t* __restrict__ WT, bf16_t* __restrict__ W3T,
                        bf16_t* __restrict__ W1T, bf16_t* __restrict__ W2T)
{
    int idx = blockIdx.x * 256 + threadIdx.x;
    if (idx >= NLAYER * 57344) return;
    int l = idx / 57344, r = idx % 57344;
    if (r < 8192) {
        int n = r >> 6, k = r & 63;
        WT[l * 8192 + r] = f2bf(Wfij[l * 8192 + k * 128 + n]);
    } else if (r < 32768) {
        int q = r - 8192; int c = q >> 6, k = q & 63;
        const float* src = (c < 128) ? Wni : (c < 256) ? Wnj : Wnode;
        W3T[l * 24576 + q] = f2bf(src[l * 8192 + k * 128 + (c & 127)]);
    } else if (r < 49152) {
        int q = r - 32768; int n = q >> 7, k = q & 127;
        W1T[l * 16384 + q] = f2bf(W1[l * 16384 + k * 128 + n]);
    } else {
        int q = r - 49152; int j = q >> 7, k = q & 127;
        W2T[l * 8192 + q] = f2bf(W2[l * 8192 + k * 64 + j]);
    }
}

// ---------------- feature encoder: h0 = gelu(feat@W1+b1)@W2+b2 ----------------
__global__ __launch_bounds__(256) void k_fe(
    const float* __restrict__ feat, const float* __restrict__ W1, const float* __restrict__ b1,
    const float* __restrict__ W2, const float* __restrict__ b2,
    float* __restrict__ h, bf16_t* __restrict__ hb, float* __restrict__ out)
{
    __shared__ float hid[4][64];
    int w = threadIdx.x >> 6, lane = threadIdx.x & 63;
    int n = blockIdx.x * 4 + w;  // N divisible by 4
    float a = b1[lane];
#pragma unroll 8
    for (int k = 0; k < 32; k++) a = fmaf(feat[n * 32 + k], W1[k * 64 + lane], a);
    hid[w][lane] = gelu_f(a);
    __syncthreads();
    float o = b2[lane];
#pragma unroll 8
    for (int k = 0; k < 64; k++) o = fmaf(hid[w][k], W2[k * 64 + lane], o);
    h[n * 64 + lane] = o;
    hb[n * 64 + lane] = f2bf(o);
    out[n * 704 + 32 + lane] = o;
    if (lane < 32) out[n * 704 + lane] = feat[n * 32 + lane];
}

// ---------------- s = h @ [W_ni | W_nj | W_node(+b)] -> [NPAD,384] bf16, MFMA ----------------
__global__ __launch_bounds__(256) void k_node3(
    const bf16_t* __restrict__ hb, const bf16_t* __restrict__ W3T,
    const float* __restrict__ bnode, bf16_t* __restrict__ s)
{
    __shared__ __align__(16) bf16_t hbS[32 * 72];
    const int t = threadIdx.x;
    const int wave = t >> 6, lane = t & 63, l16 = lane & 15, quad = lane >> 4;
    const int n0 = blockIdx.x * 32;
    {   // stage hb tile: 32 rows x 128B
        int r = t >> 3, sg = t & 7;
        *(s16x8*)(hbS + r * 72 + sg * 8) = *(const s16x8*)(hb + (size_t)(n0 + r) * 64 + sg * 8);
    }
    __syncthreads();
    const int ng = wave & 1, ch = wave >> 1;
    const s16x8 B0 = *(const s16x8*)(hbS + (ng * 16 + l16) * 72 + quad * 8);
    const s16x8 B1 = *(const s16x8*)(hbS + (ng * 16 + l16) * 72 + 32 + quad * 8);
    const int node = n0 + ng * 16 + l16;
#pragma unroll
    for (int nt = 0; nt < 12; nt++) {
        int c0 = ch * 192 + nt * 16;
        const s16x8 A0 = *(const s16x8*)(W3T + (size_t)(c0 + l16) * 64 + quad * 8);
        const s16x8 A1 = *(const s16x8*)(W3T + (size_t)(c0 + l16) * 64 + 32 + quad * 8);
        f32x4 acc = {0.f, 0.f, 0.f, 0.f};
        acc = __builtin_amdgcn_mfma_f32_16x16x32_bf16(A0, B0, acc, 0, 0, 0);
        acc = __builtin_amdgcn_mfma_f32_16x16x32_bf16(A1, B1, acc, 0, 0, 0);
        int cb = c0 + quad * 4;
        float4 bv = make_float4(0.f, 0.f, 0.f, 0.f);
        if (cb >= 256) bv = *(const float4*)(bnode + cb - 256);
        ushort4 o;
        o.x = f2bf(acc[0] + bv.x);
        o.y = f2bf(acc[1] + bv.y);
        o.z = f2bf(acc[2] + bv.z);
        o.w = f2bf(acc[3] + bv.w);
        *(ushort4*)(s + (size_t)node * 384 + cb) = o;
    }
}

// ---------------- fused edge kernel: 32 edges/wave, no LDS, no barriers ----------------
// Lane (l16, quad) owns edges iA = unit*32+l16 and iB = iA+16 (two MFMA B-groups).
// All 16 s-row gathers issue up-front (max MLP). WT/attn/rcW/rpW/base read via L1/L2.
// SND kept in fp32 (no bf16 round-trip). A-frags loaded once per (hd,mt), feed both groups.
__global__ __launch_bounds__(256) void k_edge(
    const bf16_t* __restrict__ s, const bf16_t* __restrict__ WT,
    const float* __restrict__ attn, const uint4* __restrict__ emA,
    const uint2* __restrict__ emB, const float* __restrict__ base,
    const float* __restrict__ rcW, const float* __restrict__ rpW,
    float* __restrict__ evals)
{
    const int lane = threadIdx.x & 63;
    const int l16 = lane & 15, quad = lane >> 4;
    const int unit = (blockIdx.x * 256 + threadIdx.x) >> 6;   // grid covers N_EDGES/32 exactly
    const int iA = unit * 32 + l16, iB = iA + 16;

    const uint4 mA = emA[iA], mB = emA[iB];
    const uint2 nA = emB[iA], nB = emB[iB];

    // Issue the long-latency gathers first: ni = src cols 0..63, nj = dst cols 128..191.
    ushort4 nivA[4], njvA[4], nivB[4], njvB[4];
    {
        const bf16_t* srA = s + (size_t)mA.x * 384;
        const bf16_t* drA = s + (size_t)mA.y * 384 + 128;
        const bf16_t* srB = s + (size_t)mB.x * 384;
        const bf16_t* drB = s + (size_t)mB.y * 384 + 128;
#pragma unroll
        for (int mt = 0; mt < 4; mt++) {
            const int d0 = mt * 16 + quad * 4;
            nivA[mt] = *(const ushort4*)(srA + d0);
            njvA[mt] = *(const ushort4*)(drA + d0);
            nivB[mt] = *(const ushort4*)(srB + d0);
            njvB[mt] = *(const ushort4*)(drB + d0);
        }
    }

    // ef for both edges (16 k-dims per lane): base[combo] + 5-term correction (old op order).
    const float rcA0 = bfl(mA.w), rcA1 = bfh(mA.w);
    const float rpA0 = bfl(nA.x), rpA1 = bfh(nA.x), rpA2 = bfl(nA.y);
    const float rcB0 = bfl(mB.w), rcB1 = bfh(mB.w);
    const float rpB0 = bfl(nB.x), rpB1 = bfh(nB.x), rpB2 = bfl(nB.y);
    const float* bpA = base + (size_t)mA.z * 64;
    const float* bpB = base + (size_t)mB.z * 64;

    s16x8 B0A, B1A, B0B, B1B;
#pragma unroll
    for (int s4 = 0; s4 < 4; s4++) {
        const int k = (s4 >> 1) * 32 + (s4 & 1) * 4 + quad * 8;
        const float4 w0 = *(const float4*)(rcW + k);
        const float4 w1 = *(const float4*)(rcW + 64 + k);
        const float4 w2 = *(const float4*)(rpW + k);
        const float4 w3 = *(const float4*)(rpW + 64 + k);
        const float4 w4 = *(const float4*)(rpW + 128 + k);
        const float4 bA = *(const float4*)(bpA + k);
        const float4 bB = *(const float4*)(bpB + k);
        float a0 = bA.x, a1 = bA.y, a2 = bA.z, a3 = bA.w;
        a0 = fmaf(rcA0, w0.x, a0); a1 = fmaf(rcA0, w0.y, a1); a2 = fmaf(rcA0, w0.z, a2); a3 = fmaf(rcA0, w0.w, a3);
        a0 = fmaf(rcA1, w1.x, a0); a1 = fmaf(rcA1, w1.y, a1); a2 = fmaf(rcA1, w1.z, a2); a3 = fmaf(rcA1, w1.w, a3);
        a0 = fmaf(rpA0, w2.x, a0); a1 = fmaf(rpA0, w2.y, a1); a2 = fmaf(rpA0, w2.z, a2); a3 = fmaf(rpA0, w2.w, a3);
        a0 = fmaf(rpA1, w3.x, a0); a1 = fmaf(rpA1, w3.y, a1); a2 = fmaf(rpA1, w3.z, a2); a3 = fmaf(rpA1, w3.w, a3);
        a0 = fmaf(rpA2, w4.x, a0); a1 = fmaf(rpA2, w4.y, a1); a2 = fmaf(rpA2, w4.z, a2); a3 = fmaf(rpA2, w4.w, a3);
        float b0 = bB.x, b1 = bB.y, b2 = bB.z, b3 = bB.w;
        b0 = fmaf(rcB0, w0.x, b0); b1 = fmaf(rcB0, w0.y, b1); b2 = fmaf(rcB0, w0.z, b2); b3 = fmaf(rcB0, w0.w, b3);
        b0 = fmaf(rcB1, w1.x, b0); b1 = fmaf(rcB1, w1.y, b1); b2 = fmaf(rcB1, w1.z, b2); b3 = fmaf(rcB1, w1.w, b3);
        b0 = fmaf(rpB0, w2.x, b0); b1 = fmaf(rpB0, w2.y, b1); b2 = fmaf(rpB0, w2.z, b2); b3 = fmaf(rpB0, w2.w, b3);
        b0 = fmaf(rpB1, w3.x, b0); b1 = fmaf(rpB1, w3.y, b1); b2 = fmaf(rpB1, w3.z, b2); b3 = fmaf(rpB1, w3.w, b3);
        b0 = fmaf(rpB2, w4.x, b0); b1 = fmaf(rpB2, w4.y, b1); b2 = fmaf(rpB2, w4.z, b2); b3 = fmaf(rpB2, w4.w, b3);
        const short pA0 = (short)f2bf(a0), pA1 = (short)f2bf(a1), pA2 = (short)f2bf(a2), pA3 = (short)f2bf(a3);
        const short pB0 = (short)f2bf(b0), pB1 = (short)f2bf(b1), pB2 = (short)f2bf(b2), pB3 = (short)f2bf(b3);
        const int o = (s4 & 1) * 4;
        if (s4 < 2) {
            B0A[o + 0] = pA0; B0A[o + 1] = pA1; B0A[o + 2] = pA2; B0A[o + 3] = pA3;
            B0B[o + 0] = pB0; B0B[o + 1] = pB1; B0B[o + 2] = pB2; B0B[o + 3] = pB3;
        } else {
            B1A[o + 0] = pA0; B1A[o + 1] = pA1; B1A[o + 2] = pA2; B1A[o + 3] = pA3;
            B1B[o + 0] = pB0; B1B[o + 1] = pB1; B1B[o + 2] = pB2; B1B[o + 3] = pB3;
        }
    }

    // SND in fp32 (no bf16 round-trip).
    float sndA[4][4], sndB[4][4];
#pragma unroll
    for (int mt = 0; mt < 4; mt++) {
        sndA[mt][0] = bf2f(nivA[mt].x) + bf2f(njvA[mt].x);
        sndA[mt][1] = bf2f(nivA[mt].y) + bf2f(njvA[mt].y);
        sndA[mt][2] = bf2f(nivA[mt].z) + bf2f(njvA[mt].z);
        sndA[mt][3] = bf2f(nivA[mt].w) + bf2f(njvA[mt].w);
        sndB[mt][0] = bf2f(nivB[mt].x) + bf2f(njvB[mt].x);
        sndB[mt][1] = bf2f(nivB[mt].y) + bf2f(njvB[mt].y);
        sndB[mt][2] = bf2f(nivB[mt].z) + bf2f(njvB[mt].z);
        sndB[mt][3] = bf2f(nivB[mt].w) + bf2f(njvB[mt].w);
    }

#pragma unroll
    for (int hd = 0; hd < 2; hd++) {
        float pA = 0.f, pB = 0.f;
#pragma unroll
        for (int mt = 0; mt < 4; mt++) {
            const bf16_t* arow = WT + (hd * 64 + mt * 16 + l16) * 64 + quad * 8;
            const s16x8 A0 = *(const s16x8*)(arow);
            const s16x8 A1 = *(const s16x8*)(arow + 32);
            f32x4 aA = {0.f, 0.f, 0.f, 0.f};
            aA = __builtin_amdgcn_mfma_f32_16x16x32_bf16(A0, B0A, aA, 0, 0, 0);
            aA = __builtin_amdgcn_mfma_f32_16x16x32_bf16(A1, B1A, aA, 0, 0, 0);
            f32x4 aB = {0.f, 0.f, 0.f, 0.f};
            aB = __builtin_amdgcn_mfma_f32_16x16x32_bf16(A0, B0B, aB, 0, 0, 0);
            aB = __builtin_amdgcn_mfma_f32_16x16x32_bf16(A1, B1B, aB, 0, 0, 0);
            const float4 at = *(const float4*)(attn + hd * 64 + mt * 16 + quad * 4);
            float f0 = aA[0] + sndA[mt][0];
            float f1 = aA[1] + sndA[mt][1];
            float f2 = aA[2] + sndA[mt][2];
            float f3 = aA[3] + sndA[mt][3];
            f0 = (f0 >= 0.f) ? f0 : 0.2f * f0;
            f1 = (f1 >= 0.f) ? f1 : 0.2f * f1;
            f2 = (f2 >= 0.f) ? f2 : 0.2f * f2;
            f3 = (f3 >= 0.f) ? f3 : 0.2f * f3;
            pA = fmaf(f0, at.x, pA);
            pA = fmaf(f1, at.y, pA);
            pA = fmaf(f2, at.z, pA);
            pA = fmaf(f3, at.w, pA);
            float g0 = aB[0] + sndB[mt][0];
            float g1 = aB[1] + sndB[mt][1];
            float g2 = aB[2] + sndB[mt][2];
            float g3 = aB[3] + sndB[mt][3];
            g0 = (g0 >= 0.f) ? g0 : 0.2f * g0;
            g1 = (g1 >= 0.f) ? g1 : 0.2f * g1;
            g2 = (g2 >= 0.f) ? g2 : 0.2f * g2;
            g3 = (g3 >= 0.f) ? g3 : 0.2f * g3;
            pB = fmaf(g0, at.x, pB);
            pB = fmaf(g1, at.y, pB);
            pB = fmaf(g2, at.z, pB);
            pB = fmaf(g3, at.w, pB);
        }
        pA += __shfl_xor(pA, 16);
        pA += __shfl_xor(pA, 32);
        pB += __shfl_xor(pB, 16);
        pB += __shfl_xor(pB, 32);
        if (quad == 0) {
            evals[iA * 2 + hd] = pA;
            evals[iB * 2 + hd] = pB;
        }
    }
}

// ---------------- per-dst softmax + aggregation -> aggb bf16 ----------------
// Paired-edge gather: lanes 0-31 even edges, 32-63 odd edges; lane owns 4 dims (8 B load).
// Per-head stats in 32-lane head-groups (bit4 = head) via shfl_xor {1,2,4,8,32}.
__global__ __launch_bounds__(256) void k_soft_agg(
    const int* __restrict__ rowptr, const int* __restrict__ src_s,
    const float* __restrict__ evals, const bf16_t* __restrict__ s,
    unsigned* __restrict__ aggb)   // [NPAD][64] uints = [NPAD][128] bf16
{
    int lane = threadIdx.x & 63;
    int wid = (blockIdx.x * 256 + threadIdx.x) >> 6;
    int nw = (gridDim.x * 256) >> 6;
    const int hb = (lane >> 4) & 1;                    // head for this lane's dims
    const int esel = lane >> 5;                        // 0: even edge of pair, 1: odd
    const int s32 = (lane & 15) | ((lane >> 5) << 4);  // 0..31 within head-group
    const int dsel = (lane & 31) * 4;                  // 4 bf16 dims per lane
    for (int n = wid; n < N_NODES; n += nw) {
        int r0 = rowptr[n], r1 = rowptr[n + 1];
        if (r0 == r1) {
            if (lane < 32) { uint2 z; z.x = 0u; z.y = 0u; *(uint2*)(aggb + (size_t)n * 64 + lane * 2) = z; }
            continue;
        }
        float mm = -1e30f;
        for (int i = r0 + s32; i < r1; i += 32) mm = fmaxf(mm, evals[2 * i + hb]);
        mm = fmaxf(mm, __shfl_xor(mm, 1));
        mm = fmaxf(mm, __shfl_xor(mm, 2));
        mm = fmaxf(mm, __shfl_xor(mm, 4));
        mm = fmaxf(mm, __shfl_xor(mm, 8));
        mm = fmaxf(mm, __shfl_xor(mm, 32));
        float z = 0.f;
        for (int i = r0 + s32; i < r1; i += 32) z += expf(evals[2 * i + hb] - mm);
        z += __shfl_xor(z, 1);
        z += __shfl_xor(z, 2);
        z += __shfl_xor(z, 4);
        z += __shfl_xor(z, 8);
        z += __shfl_xor(z, 32);
        float rz = 1.f / z;
        float acc0 = 0.f, acc1 = 0.f, acc2 = 0.f, acc3 = 0.f;
        for (int i = r0; i < r1; i += 8) {
            uint2 cc[4]; float ww[4];
#pragma unroll
            for (int p = 0; p < 4; p++) {
                int ej = i + 2 * p + esel;
                bool v = ej < r1;
                int es = v ? ej : r0;
                cc[p] = *(const uint2*)(s + (size_t)src_s[es] * 384 + 256 + dsel);
                ww[p] = v ? expf(evals[2 * ej + hb] - mm) * rz : 0.f;
            }
#pragma unroll
            for (int p = 0; p < 4; p++) {
                acc0 = fmaf(ww[p], bfl(cc[p].x), acc0);
                acc1 = fmaf(ww[p], bfh(cc[p].x), acc1);
                acc2 = fmaf(ww[p], bfl(cc[p].y), acc2);
                acc3 = fmaf(ww[p], bfh(cc[p].y), acc3);
            }
        }
        acc0 += __shfl_xor(acc0, 32);
        acc1 += __shfl_xor(acc1, 32);
        acc2 += __shfl_xor(acc2, 32);
        acc3 += __shfl_xor(acc3, 32);
        if (lane < 32) {
            uint2 o;
            o.x = (unsigned)f2bf(acc0) | ((unsigned)f2bf(acc1) << 16);
            o.y = (unsigned)f2bf(acc2) | ((unsigned)f2bf(acc3) << 16);
            *(uint2*)(aggb + (size_t)n * 64 + lane * 2) = o;
        }
    }
}

// ---------------- node MLP + residual, MFMA: h' = gelu(agg@W1+b1)@W2+b2 + h ----------------
__global__ __launch_bounds__(256) void k_mlp(
    const bf16_t* __restrict__ aggb, const bf16_t* __restrict__ W1T, const float* __restrict__ b1,
    const bf16_t* __restrict__ W2T, const float* __restrict__ b2,
    const float* __restrict__ hin, float* __restrict__ hout, bf16_t* __restrict__ houtb,
    float* __restrict__ out, int col0)
{
    __shared__ __align__(16) bf16_t aggS[32 * 136];
    __shared__ __align__(16) bf16_t hidS[32 * 136];
    const int t = threadIdx.x;
    const int wave = t >> 6, lane = t & 63, l16 = lane & 15, quad = lane >> 4;
    const int n0 = blockIdx.x * 32;
    {   // stage agg tile: 32 rows x 256B (32B per thread)
        int r = t >> 3, sg = t & 7;
        *(s16x8*)(aggS + r * 136 + sg * 16) =
            *(const s16x8*)(aggb + (size_t)(n0 + r) * 128 + sg * 16);
        *(s16x8*)(aggS + r * 136 + sg * 16 + 8) =
            *(const s16x8*)(aggb + (size_t)(n0 + r) * 128 + sg * 16 + 8);
    }
    __syncthreads();
    const int ng = wave & 1, nh = wave >> 1;
    const int node = n0 + ng * 16 + l16;
    {   // GEMM1 + gelu -> hidS
        const bf16_t* brow = aggS + (ng * 16 + l16) * 136 + quad * 8;
        s16x8 B[4];
#pragma unroll
        for (int ks = 0; ks < 4; ks++) B[ks] = *(const s16x8*)(brow + ks * 32);
#pragma unroll
        for (int nt = 0; nt < 4; nt++) {
            int nb = nh * 64 + nt * 16;
            f32x4 acc = {0.f, 0.f, 0.f, 0.f};
#pragma unroll
            for (int ks = 0; ks < 4; ks++) {
                const s16x8 A = *(const s16x8*)(W1T + (size_t)(nb + l16) * 128 + ks * 32 + quad * 8);
                acc = __builtin_amdgcn_mfma_f32_16x16x32_bf16(A, B[ks], acc, 0, 0, 0);
            }
            const float4 bv = *(const float4*)(b1 + nb + quad * 4);
            ushort4 o;
            o.x = f2bf(gelu_f(acc[0] + bv.x));
            o.y = f2bf(gelu_f(acc[1] + bv.y));
            o.z = f2bf(gelu_f(acc[2] + bv.z));
            o.w = f2bf(gelu_f(acc[3] + bv.w));
            *(ushort4*)(hidS + (ng * 16 + l16) * 136 + nb + quad * 4) = o;
        }
    }
    __syncthreads();
    {   // GEMM2 + bias + residual -> hout/houtb/out
        const int jh = wave >> 1;
        const bf16_t* hrow = hidS + (ng * 16 + l16) * 136 + quad * 8;
        s16x8 H[4];
#pragma unroll
        for (int ks = 0; ks < 4; ks++) H[ks] = *(const s16x8*)(hrow + ks * 32);
#pragma unroll
        for (int jt = 0; jt < 2; jt++) {
            int jb = jh * 32 + jt * 16;
            f32x4 acc = {0.f, 0.f, 0.f, 0.f};
#pragma unroll
            for (int ks = 0; ks < 4; ks++) {
                const s16x8 A = *(const s16x8*)(W2T + (size_t)(jb + l16) * 128 + ks * 32 + quad * 8);
                acc = __builtin_amdgcn_mfma_f32_16x16x32_bf16(A, H[ks], acc, 0, 0, 0);
            }
            int j0 = jb + quad * 4;
            const float4 bv = *(const float4*)(b2 + j0);
            const float4 hv = *(const float4*)(hin + (size_t)node * 64 + j0);
            float4 v;
            v.x = acc[0] + bv.x + hv.x;
            v.y = acc[1] + bv.y + hv.y;
            v.z = acc[2] + bv.z + hv.z;
            v.w = acc[3] + bv.w + hv.w;
            *(float4*)(hout + (size_t)node * 64 + j0) = v;
            ushort4 ob;
            ob.x = f2bf(v.x); ob.y = f2bf(v.y); ob.z = f2bf(v.z); ob.w = f2bf(v.w);
            *(ushort4*)(houtb + (size_t)node * 64 + j0) = ob;
            if (node < N_NODES)
                *(float4*)(out + (size_t)node * 704 + col0 + j0) = v;
        }
    }
}

// ---------------- graph max pooling over node_emb cols 0..351 ----------------
__device__ __forceinline__ unsigned fmap(float v) {
    unsigned u = __float_as_uint(v);
    return (u & 0x80000000u) ? ~u : (u | 0x80000000u);
}

__global__ __launch_bounds__(384) void k_colmax(const float* __restrict__ out, unsigned* __restrict__ gmax) {
    int c = threadIdx.x;
    if (c >= 352) return;
    float m = -1e30f;
    for (int n = blockIdx.x; n < N_NODES; n += gridDim.x)
        m = fmaxf(m, out[(size_t)n * 704 + c]);
    atomicMax(gmax + c, fmap(m));
}

__global__ __launch_bounds__(384) void k_bcast(const unsigned* __restrict__ gmax, float* __restrict__ out) {
    int c = threadIdx.x;
    if (c >= 352) return;
    unsigned u = gmax[c];
    u = (u & 0x80000000u) ? (u ^ 0x80000000u) : ~u;
    float v = __uint_as_float(u);
    for (int n = blockIdx.x; n < N_NODES; n += gridDim.x)
        out[(size_t)n * 704 + 352 + c] = v;
}

// ---------------- host launcher ----------------
extern "C" void kernel_launch(void* const* d_in, const int* in_sizes, int n_in,
                              void* d_out, int out_size, void* d_ws, size_t ws_size,
                              hipStream_t stream)
{
    (void)in_sizes; (void)n_in; (void)out_size; (void)ws_size;
    const float* feat     = (const float*)d_in[0];
    const float* att_rc   = (const float*)d_in[1];
    const float* att_rp   = (const float*)d_in[2];
    const float* type_emb = (const float*)d_in[3];
    const float* rid_emb  = (const float*)d_in[4];
    const float* rc_W     = (const float*)d_in[5];
    const float* rc_b     = (const float*)d_in[6];
    const float* rp_W     = (const float*)d_in[7];
    const float* rp_b     = (const float*)d_in[8];
    const float* fe_W1    = (const float*)d_in[9];
    const float* fe_b1    = (const float*)d_in[10];
    const float* fe_W2    = (const float*)d_in[11];
    const float* fe_b2    = (const float*)d_in[12];
    const float* W_ni     = (const float*)d_in[13];
    const float* W_nj     = (const float*)d_in[14];
    const float* W_fij    = (const float*)d_in[15];
    const float* W_node   = (const float*)d_in[16];
    const float* b_node   = (const float*)d_in[17];
    const float* attn     = (const float*)d_in[18];
    const float* mlp_W1   = (const float*)d_in[19];
    const float* mlp_b1   = (const float*)d_in[20];
    const float* mlp_W2   = (const float*)d_in[21];
    const float* mlp_b2   = (const float*)d_in[22];
    const int* src   = (const int*)d_in[23];
    const int* dst   = (const int*)d_in[24];
    const int* etype = (const int*)d_in[25];
    const int* erid  = (const int*)d_in[26];
    float* out = (float*)d_out;

    // Workspace layout (byte cursor, all chunks 16B aligned).
    char* cur = (char*)d_ws;
    auto alloc = [&](size_t bytes) { char* p = cur; cur += (bytes + 15) & ~(size_t)15; return p; };
    float* h_a    = (float*)alloc((size_t)NPAD * 64 * 4);
    float* h_b    = (float*)alloc((size_t)NPAD * 64 * 4);
    bf16_t* hb_a  = (bf16_t*)alloc((size_t)NPAD * 64 * 2);
    bf16_t* hb_b  = (bf16_t*)alloc((size_t)NPAD * 64 * 2);
    bf16_t* s     = (bf16_t*)alloc((size_t)NPAD * 384 * 2);
    float* ev     = (float*)alloc((size_t)N_EDGES * 2 * 4);
    bf16_t* aggb  = (bf16_t*)alloc((size_t)NPAD * 128 * 2);
    int* deg     = (int*)alloc((size_t)N_NODES * 4);
    int* rowptr  = (int*)alloc((size_t)(N_NODES + 1) * 4);
    int* cursor  = (int*)alloc((size_t)N_NODES * 4);
    int* eidx    = (int*)alloc((size_t)N_EDGES * 4);
    int* src_s   = (int*)alloc((size_t)N_EDGES * 4);
    uint4* emA   = (uint4*)alloc((size_t)N_EDGES * 16);
    uint2* emB   = (uint2*)alloc((size_t)N_EDGES * 8);
    float* baseT = (float*)alloc((size_t)315 * 64 * 4);
    bf16_t* WT   = (bf16_t*)alloc((size_t)NLAYER * 128 * 64 * 2);
    bf16_t* W3T  = (bf16_t*)alloc((size_t)NLAYER * 384 * 64 * 2);
    bf16_t* W1T  = (bf16_t*)alloc((size_t)NLAYER * 128 * 128 * 2);
    bf16_t* W2T  = (bf16_t*)alloc((size_t)NLAYER * 64 * 128 * 2);
    int* bsum    = (int*)alloc(64 * 4);
    int* boff    = (int*)alloc(64 * 4);
    unsigned* gmax = (unsigned*)alloc(352 * 4);

    const int NB = (N_NODES + 1023) / 1024;  // 49

    k_zero32<<<(N_NODES + 255) / 256, 256, 0, stream>>>((unsigned*)deg, N_NODES);
    k_zero32<<<2, 256, 0, stream>>>(gmax, 352);
    k_hist<<<N_EDGES / 256, 256, 0, stream>>>(dst, deg);
    k_scan1<<<NB, 1024, 0, stream>>>(deg, rowptr, bsum);
    k_scan2<<<1, 64, 0, stream>>>(bsum, boff, NB);
    k_scan3<<<NB, 1024, 0, stream>>>(rowptr, boff);
    k_copy<<<(N_NODES + 255) / 256, 256, 0, stream>>>(rowptr, cursor);
    k_scatter<<<N_EDGES / 256, 256, 0, stream>>>(dst, cursor, eidx);
    k_sortgather<<<N_EDGES / 256, 256, 0, stream>>>(eidx, src, dst, etype, erid, att_rc, att_rp,
                                                    src_s, emA, emB);
    k_base<<<(315 * 64 + 255) / 256, 256, 0, stream>>>(type_emb, rid_emb, rc_b, rp_b, baseT);
    k_wprep<<<(NLAYER * 57344 + 255) / 256, 256, 0, stream>>>(
        W_fij, W_ni, W_nj, W_node, mlp_W1, mlp_W2, WT, W3T, W1T, W2T);
    k_fe<<<N_NODES / 4, 256, 0, stream>>>(feat, fe_W1, fe_b1, fe_W2, fe_b2, h_a, hb_a, out);

    float* hc = h_a;  bf16_t* hbc = hb_a;
    float* hn = h_b;  bf16_t* hbn = hb_b;
    for (int l = 0; l < NLAYER; l++) {
        k_node3<<<NPAD / 32, 256, 0, stream>>>(hbc, W3T + (size_t)l * 384 * 64, b_node + l * 128, s);
        k_edge<<<N_EDGES / 128, 256, 0, stream>>>(s, WT + l * 128 * 64, attn + l * 128,
                                                  emA, emB, baseT, rc_W, rp_W, ev);
        k_soft_agg<<<4096, 256, 0, stream>>>(rowptr, src_s, ev, s, (unsigned*)aggb);
        k_mlp<<<NPAD / 32, 256, 0, stream>>>(aggb, W1T + (size_t)l * 128 * 128, mlp_b1 + l * 128,
                                             W2T + (size_t)l * 64 * 128, mlp_b2 + l * 64,
                                             hc, hn, hbn, out, 32 + 64 * (l + 1));
        float* tf = hc; hc = hn; hn = tf;
        bf16_t* tb = hbc; hbc = hbn; hbn = tb;
    }
    k_colmax<<<512, 384, 0, stream>>>(out, gmax);
    k_bcast<<<512, 384, 0, stream>>>(gmax, out);
}

// Round 5
// 1258.263 us; speedup vs baseline: 1.0048x; 1.0048x over previous
//
#include <hip/hip_runtime.h>
#include <math.h>

// Problem constants (fixed by the reference).
#define N_NODES 50000
#define N_EDGES 640000   // divisible by 32 (20000 tiles) and 256
#define NLAYER  4
#define NPAD    50016    // N_NODES rounded up to 32

// k_edge pipeline geometry: 40000 tiles of 16 edges; 1000 blocks x 4 waves = 4000 waves
// -> exactly 10 tiles per wave (5 unrolled A/B pairs).
#define EDGE_BLOCKS 1000
#define EDGE_WAVES  4000

typedef unsigned short bf16_t;
typedef __attribute__((ext_vector_type(8))) short s16x8;   // 8 bf16 = 4 VGPR (MFMA A/B frag)
typedef __attribute__((ext_vector_type(4))) float f32x4;   // MFMA C/D frag

__device__ __forceinline__ float gelu_f(float x) {
    return 0.5f * x * (1.0f + tanhf(0.7978845608028654f * (x + 0.044715f * x * x * x)));
}

__device__ __forceinline__ bf16_t f2bf(float f) {
    unsigned u = __float_as_uint(f);
    unsigned r = (u + 0x7FFFu + ((u >> 16) & 1u)) >> 16;   // RNE
    return (bf16_t)r;
}
__device__ __forceinline__ float bf2f(bf16_t h) { return __uint_as_float(((unsigned)h) << 16); }
__device__ __forceinline__ float bfl(unsigned x) { return __uint_as_float(x << 16); }
__device__ __forceinline__ float bfh(unsigned x) { return __uint_as_float(x & 0xFFFF0000u); }

// ---------------- CSR build (counting sort by dst) ----------------
__global__ void k_zero32(unsigned* p, int n) {
    int i = blockIdx.x * 256 + threadIdx.x;
    if (i < n) p[i] = 0u;
}

__global__ void k_hist(const int* __restrict__ dst, int* __restrict__ deg) {
    int i = blockIdx.x * 256 + threadIdx.x;
    if (i < N_EDGES) atomicAdd(&deg[dst[i]], 1);
}

__global__ void k_scan1(const int* __restrict__ deg, int* __restrict__ rowptr, int* __restrict__ bsum) {
    __shared__ int sd[1024];
    int gi = blockIdx.x * 1024 + threadIdx.x;
    int v = (gi < N_NODES) ? deg[gi] : 0;
    sd[threadIdx.x] = v;
    __syncthreads();
    for (int off = 1; off < 1024; off <<= 1) {
        int t2 = (threadIdx.x >= (unsigned)off) ? sd[threadIdx.x - off] : 0;
        __syncthreads();
        sd[threadIdx.x] += t2;
        __syncthreads();
    }
    if (gi < N_NODES) rowptr[gi] = sd[threadIdx.x] - v;  // block-local exclusive
    if (threadIdx.x == 1023) bsum[blockIdx.x] = sd[1023];
}

__global__ void k_scan2(const int* __restrict__ bsum, int* __restrict__ boff, int nb) {
    if (threadIdx.x == 0 && blockIdx.x == 0) {
        int run = 0;
        for (int b = 0; b < nb; b++) { boff[b] = run; run += bsum[b]; }
    }
}

__global__ void k_scan3(int* __restrict__ rowptr, const int* __restrict__ boff) {
    int gi = blockIdx.x * 1024 + threadIdx.x;
    if (gi < N_NODES) rowptr[gi] += boff[blockIdx.x];
    if (gi == 0) rowptr[N_NODES] = N_EDGES;
}

__global__ void k_copy(const int* __restrict__ a, int* __restrict__ b) {
    int i = blockIdx.x * 256 + threadIdx.x;
    if (i < N_NODES) b[i] = a[i];
}

__global__ void k_scatter(const int* __restrict__ dst, int* __restrict__ cursor, int* __restrict__ eidx) {
    int i = blockIdx.x * 256 + threadIdx.x;
    if (i < N_EDGES) {
        int p = atomicAdd(&cursor[dst[i]], 1);
        eidx[p] = i;
    }
}

// Gather per-edge fields into dst-sorted order, compact 24 B/edge:
// emA[i] = { src, dst, combo = etype*9+erid, rc0|rc1<<16 (bf16) }
// emB[i] = { rp0|rp1<<16 (bf16), rp2 (bf16) }
__global__ void k_sortgather(
    const int* __restrict__ eidx, const int* __restrict__ src, const int* __restrict__ dst,
    const int* __restrict__ etype, const int* __restrict__ erid,
    const float* __restrict__ att_rc, const float* __restrict__ att_rp,
    int* __restrict__ src_s, uint4* __restrict__ emA, uint2* __restrict__ emB)
{
    int i = blockIdx.x * 256 + threadIdx.x;
    if (i < N_EDGES) {
        int e = eidx[i];
        int sv = src[e];
        src_s[i] = sv;
        uint4 a;
        a.x = (unsigned)sv;
        a.y = (unsigned)dst[e];
        a.z = (unsigned)(etype[e] * 9 + erid[e]);
        a.w = (unsigned)f2bf(att_rc[2 * e]) | ((unsigned)f2bf(att_rc[2 * e + 1]) << 16);
        uint2 b;
        b.x = (unsigned)f2bf(att_rp[3 * e]) | ((unsigned)f2bf(att_rp[3 * e + 1]) << 16);
        b.y = (unsigned)f2bf(att_rp[3 * e + 2]);
        emA[i] = a;
        emB[i] = b;
    }
}

// ---------------- (etype,erid)-combo base table: 315 x 64 fp32 (~80 KB, cache-hot) ----------
__global__ void k_base(const float* __restrict__ type_emb, const float* __restrict__ rid_emb,
                       const float* __restrict__ rcb, const float* __restrict__ rpb,
                       float* __restrict__ base)
{
    int idx = blockIdx.x * 256 + threadIdx.x;
    if (idx >= 315 * 64) return;
    int c = idx >> 6, k = idx & 63;
    int et = c / 9, er = c % 9;
    base[idx] = type_emb[et * 64 + k] + rid_emb[er * 64 + k] + rcb[k] + rpb[k];
}

// Weight transposes to bf16, k-contiguous rows (MFMA A-operand friendly).
__global__ void k_wprep(const float* __restrict__ Wfij, const float* __restrict__ Wni,
                        const float* __restrict__ Wnj, const float* __restrict__ Wnode,
                        const float* __restrict__ W1, const float* __restrict__ W2,
                        bf16_t* __restrict__ WT, bf16_t* __restrict__ W3T,
                        bf16_t* __restrict__ W1T, bf16_t* __restrict__ W2T)
{
    int idx = blockIdx.x * 256 + threadIdx.x;
    if (idx >= NLAYER * 57344) return;
    int l = idx / 57344, r = idx % 57344;
    if (r < 8192) {
        int n = r >> 6, k = r & 63;
        WT[l * 8192 + r] = f2bf(Wfij[l * 8192 + k * 128 + n]);
    } else if (r < 32768) {
        int q = r - 8192; int c = q >> 6, k = q & 63;
        const float* src = (c < 128) ? Wni : (c < 256) ? Wnj : Wnode;
        W3T[l * 24576 + q] = f2bf(src[l * 8192 + k * 128 + (c & 127)]);
    } else if (r < 49152) {
        int q = r - 32768; int n = q >> 7, k = q & 127;
        W1T[l * 16384 + q] = f2bf(W1[l * 16384 + k * 128 + n]);
    } else {
        int q = r - 49152; int j = q >> 7, k = q & 127;
        W2T[l * 8192 + q] = f2bf(W2[l * 8192 + k * 64 + j]);
    }
}

// ---------------- feature encoder: h0 = gelu(feat@W1+b1)@W2+b2 ----------------
__global__ __launch_bounds__(256) void k_fe(
    const float* __restrict__ feat, const float* __restrict__ W1, const float* __restrict__ b1,
    const float* __restrict__ W2, const float* __restrict__ b2,
    float* __restrict__ h, bf16_t* __restrict__ hb, float* __restrict__ out)
{
    __shared__ float hid[4][64];
    int w = threadIdx.x >> 6, lane = threadIdx.x & 63;
    int n = blockIdx.x * 4 + w;  // N divisible by 4
    float a = b1[lane];
#pragma unroll 8
    for (int k = 0; k < 32; k++) a = fmaf(feat[n * 32 + k], W1[k * 64 + lane], a);
    hid[w][lane] = gelu_f(a);
    __syncthreads();
    float o = b2[lane];
#pragma unroll 8
    for (int k = 0; k < 64; k++) o = fmaf(hid[w][k], W2[k * 64 + lane], o);
    h[n * 64 + lane] = o;
    hb[n * 64 + lane] = f2bf(o);
    out[n * 704 + 32 + lane] = o;
    if (lane < 32) out[n * 704 + lane] = feat[n * 32 + lane];
}

// ---------------- s = h @ [W_ni | W_nj | W_node(+b)] -> [NPAD,384] bf16, MFMA ----------------
__global__ __launch_bounds__(256) void k_node3(
    const bf16_t* __restrict__ hb, const bf16_t* __restrict__ W3T,
    const float* __restrict__ bnode, bf16_t* __restrict__ s)
{
    __shared__ __align__(16) bf16_t hbS[32 * 72];
    const int t = threadIdx.x;
    const int wave = t >> 6, lane = t & 63, l16 = lane & 15, quad = lane >> 4;
    const int n0 = blockIdx.x * 32;
    {   // stage hb tile: 32 rows x 128B
        int r = t >> 3, sg = t & 7;
        *(s16x8*)(hbS + r * 72 + sg * 8) = *(const s16x8*)(hb + (size_t)(n0 + r) * 64 + sg * 8);
    }
    __syncthreads();
    const int ng = wave & 1, ch = wave >> 1;
    const s16x8 B0 = *(const s16x8*)(hbS + (ng * 16 + l16) * 72 + quad * 8);
    const s16x8 B1 = *(const s16x8*)(hbS + (ng * 16 + l16) * 72 + 32 + quad * 8);
    const int node = n0 + ng * 16 + l16;
#pragma unroll
    for (int nt = 0; nt < 12; nt++) {
        int c0 = ch * 192 + nt * 16;
        const s16x8 A0 = *(const s16x8*)(W3T + (size_t)(c0 + l16) * 64 + quad * 8);
        const s16x8 A1 = *(const s16x8*)(W3T + (size_t)(c0 + l16) * 64 + 32 + quad * 8);
        f32x4 acc = {0.f, 0.f, 0.f, 0.f};
        acc = __builtin_amdgcn_mfma_f32_16x16x32_bf16(A0, B0, acc, 0, 0, 0);
        acc = __builtin_amdgcn_mfma_f32_16x16x32_bf16(A1, B1, acc, 0, 0, 0);
        int cb = c0 + quad * 4;
        float4 bv = make_float4(0.f, 0.f, 0.f, 0.f);
        if (cb >= 256) bv = *(const float4*)(bnode + cb - 256);
        ushort4 o;
        o.x = f2bf(acc[0] + bv.x);
        o.y = f2bf(acc[1] + bv.y);
        o.z = f2bf(acc[2] + bv.z);
        o.w = f2bf(acc[3] + bv.w);
        *(ushort4*)(s + (size_t)node * 384 + cb) = o;
    }
}

// ---------------- fused edge kernel: software-pipelined, LDS weights, no in-loop barriers ------
// 4000 persistent waves x exactly 10 tiles of 16 edges. Gathers + meta for tile t+1 are issued
// before processing tile t (1-deep pipeline, 2x-unrolled with named buffers GA/GB).
// Weights live in LDS (lgkm pipe): A-frags in lane-linear chunks (conflict-free ds_read_b128),
// attn + rc/rp correction rows broadcast. VMEM pipe carries only gathers/meta/base.
__device__ __forceinline__ void eg_issue(
    const bf16_t* __restrict__ s, const uint4& ma, int quad, ushort4 (&G)[8])
{
    const bf16_t* sr = s + (size_t)ma.x * 384;          // ni cols 0..63
    const bf16_t* dr = s + (size_t)ma.y * 384 + 128;    // nj cols 0..63
#pragma unroll
    for (int mt = 0; mt < 4; mt++) {
        const int d0 = mt * 16 + quad * 4;
        G[mt]     = *(const ushort4*)(sr + d0);
        G[4 + mt] = *(const ushort4*)(dr + d0);
    }
}

__device__ __forceinline__ void eg_process(
    int i, const uint4& ma, const uint2& mb, const ushort4 (&G)[8],
    const bf16_t* __restrict__ WTs, const float* __restrict__ attL,
    const float (*__restrict__ cwL)[64], const float* __restrict__ base,
    int lane, int quad, float* __restrict__ evals)
{
    const float rc0 = bfl(ma.w), rc1 = bfh(ma.w);
    const float rp0 = bfl(mb.x), rp1 = bfh(mb.x), rp2 = bfl(mb.y);
    const float* bp = base + (size_t)ma.z * 64;
    s16x8 B0, B1;
#pragma unroll
    for (int s4 = 0; s4 < 4; s4++) {
        const int k = (s4 >> 1) * 32 + (s4 & 1) * 4 + quad * 8;
        const float4 bv = *(const float4*)(bp + k);
        const float4 w0 = *(const float4*)(&cwL[0][k]);
        const float4 w1 = *(const float4*)(&cwL[1][k]);
        const float4 w2 = *(const float4*)(&cwL[2][k]);
        const float4 w3 = *(const float4*)(&cwL[3][k]);
        const float4 w4 = *(const float4*)(&cwL[4][k]);
        float v0 = bv.x, v1 = bv.y, v2 = bv.z, v3 = bv.w;
        v0 = fmaf(rc0, w0.x, v0); v1 = fmaf(rc0, w0.y, v1); v2 = fmaf(rc0, w0.z, v2); v3 = fmaf(rc0, w0.w, v3);
        v0 = fmaf(rc1, w1.x, v0); v1 = fmaf(rc1, w1.y, v1); v2 = fmaf(rc1, w1.z, v2); v3 = fmaf(rc1, w1.w, v3);
        v0 = fmaf(rp0, w2.x, v0); v1 = fmaf(rp0, w2.y, v1); v2 = fmaf(rp0, w2.z, v2); v3 = fmaf(rp0, w2.w, v3);
        v0 = fmaf(rp1, w3.x, v0); v1 = fmaf(rp1, w3.y, v1); v2 = fmaf(rp1, w3.z, v2); v3 = fmaf(rp1, w3.w, v3);
        v0 = fmaf(rp2, w4.x, v0); v1 = fmaf(rp2, w4.y, v1); v2 = fmaf(rp2, w4.z, v2); v3 = fmaf(rp2, w4.w, v3);
        const short p0 = (short)f2bf(v0), p1 = (short)f2bf(v1), p2 = (short)f2bf(v2), p3 = (short)f2bf(v3);
        const int o = (s4 & 1) * 4;
        if (s4 < 2) { B0[o] = p0; B0[o + 1] = p1; B0[o + 2] = p2; B0[o + 3] = p3; }
        else        { B1[o] = p0; B1[o + 1] = p1; B1[o + 2] = p2; B1[o + 3] = p3; }
    }
#pragma unroll
    for (int hd = 0; hd < 2; hd++) {
        float p = 0.f;
#pragma unroll
        for (int mt = 0; mt < 4; mt++) {
            const int fm = hd * 4 + mt;
            const s16x8 A0 = *(const s16x8*)(WTs + ((fm * 2 + 0) * 64 + lane) * 8);
            const s16x8 A1 = *(const s16x8*)(WTs + ((fm * 2 + 1) * 64 + lane) * 8);
            f32x4 a = {0.f, 0.f, 0.f, 0.f};
            a = __builtin_amdgcn_mfma_f32_16x16x32_bf16(A0, B0, a, 0, 0, 0);
            a = __builtin_amdgcn_mfma_f32_16x16x32_bf16(A1, B1, a, 0, 0, 0);
            const float4 at = *(const float4*)(attL + hd * 64 + mt * 16 + quad * 4);
            float f0 = a[0] + (bf2f(G[mt].x) + bf2f(G[4 + mt].x));
            float f1 = a[1] + (bf2f(G[mt].y) + bf2f(G[4 + mt].y));
            float f2 = a[2] + (bf2f(G[mt].z) + bf2f(G[4 + mt].z));
            float f3 = a[3] + (bf2f(G[mt].w) + bf2f(G[4 + mt].w));
            f0 = (f0 >= 0.f) ? f0 : 0.2f * f0;
            f1 = (f1 >= 0.f) ? f1 : 0.2f * f1;
            f2 = (f2 >= 0.f) ? f2 : 0.2f * f2;
            f3 = (f3 >= 0.f) ? f3 : 0.2f * f3;
            p = fmaf(f0, at.x, p);
            p = fmaf(f1, at.y, p);
            p = fmaf(f2, at.z, p);
            p = fmaf(f3, at.w, p);
        }
        p += __shfl_xor(p, 16);
        p += __shfl_xor(p, 32);
        if (quad == 0) evals[i * 2 + hd] = p;
    }
}

__global__ __launch_bounds__(256) void k_edge(
    const bf16_t* __restrict__ s, const bf16_t* __restrict__ WT,
    const float* __restrict__ attn, const uint4* __restrict__ emA,
    const uint2* __restrict__ emB, const float* __restrict__ base,
    const float* __restrict__ rcW, const float* __restrict__ rpW,
    float* __restrict__ evals)
{
    __shared__ __align__(16) bf16_t WTs[16 * 64 * 8];   // [fm*2+half][lane] 16B chunks, 16 KB
    __shared__ __align__(16) float attL[128];
    __shared__ __align__(16) float cwL[5][64];
    for (int c = threadIdx.x; c < 1024; c += 256) {
        int ln = c & 63, rowq = c >> 6;            // rowq = fm*2+half
        int half = rowq & 1, fm = rowq >> 1;
        int rl16 = ln & 15, rq = ln >> 4;
        int grow = (fm >> 2) * 64 + (fm & 3) * 16 + rl16;   // hd*64 + mt*16 + l16
        *(s16x8*)(WTs + c * 8) = *(const s16x8*)(WT + grow * 64 + half * 32 + rq * 8);
    }
    if (threadIdx.x < 128) attL[threadIdx.x] = attn[threadIdx.x];
    {
        int j = threadIdx.x >> 6, k = threadIdx.x & 63;    // j in [0,4)
        cwL[j][k] = (j < 2) ? rcW[j * 64 + k] : rpW[(j - 2) * 64 + k];
        if (threadIdx.x < 64) cwL[4][threadIdx.x] = rpW[128 + threadIdx.x];
    }
    __syncthreads();

    const int lane = threadIdx.x & 63;
    const int l16 = lane & 15, quad = lane >> 4;
    const int wid = (blockIdx.x * 256 + threadIdx.x) >> 6;   // 0..3999

    ushort4 GA[8], GB[8];
    // Prologue: tile wid -> GA; meta for tile wid+EDGE_WAVES preloaded.
    uint4 maC = emA[wid * 16 + l16];
    uint2 mbC = emB[wid * 16 + l16];
    eg_issue(s, maC, quad, GA);
    uint4 maN = emA[(wid + EDGE_WAVES) * 16 + l16];
    uint2 mbN = emB[(wid + EDGE_WAVES) * 16 + l16];

#pragma unroll 1
    for (int it = 0; it < 5; it++) {
        const int ta = wid + (2 * it) * EDGE_WAVES;
        const int tb = ta + EDGE_WAVES;
        eg_issue(s, maN, quad, GB);                       // gathers for tb
        const bool h = it < 4;
        uint4 ma2 = maC; uint2 mb2 = mbC;
        if (h) {
            int e2 = (tb + EDGE_WAVES) * 16 + l16;
            ma2 = emA[e2]; mb2 = emB[e2];
        }
        eg_process(ta * 16 + l16, maC, mbC, GA, WTs, attL, cwL, base, lane, quad, evals);
        if (h) eg_issue(s, ma2, quad, GA);                // gathers for tb+EDGE_WAVES
        uint4 ma3 = maN; uint2 mb3 = mbN;
        if (h) {
            int e3 = (tb + 2 * EDGE_WAVES) * 16 + l16;
            ma3 = emA[e3]; mb3 = emB[e3];
        }
        eg_process(tb * 16 + l16, maN, mbN, GB, WTs, attL, cwL, base, lane, quad, evals);
        maC = ma2; mbC = mb2; maN = ma3; mbN = mb3;
    }
}

// ---------------- per-dst softmax + aggregation -> aggb bf16 ----------------
// Paired-edge gather: lanes 0-31 even edges, 32-63 odd edges; lane owns 4 dims (8 B load).
// Per-head stats in 32-lane head-groups (bit4 = head) via shfl_xor {1,2,4,8,32}.
__global__ __launch_bounds__(256) void k_soft_agg(
    const int* __restrict__ rowptr, const int* __restrict__ src_s,
    const float* __restrict__ evals, const bf16_t* __restrict__ s,
    unsigned* __restrict__ aggb)   // [NPAD][64] uints = [NPAD][128] bf16
{
    int lane = threadIdx.x & 63;
    int wid = (blockIdx.x * 256 + threadIdx.x) >> 6;
    int nw = (gridDim.x * 256) >> 6;
    const int hb = (lane >> 4) & 1;                    // head for this lane's dims
    const int esel = lane >> 5;                        // 0: even edge of pair, 1: odd
    const int s32 = (lane & 15) | ((lane >> 5) << 4);  // 0..31 within head-group
    const int dsel = (lane & 31) * 4;                  // 4 bf16 dims per lane
    for (int n = wid; n < N_NODES; n += nw) {
        int r0 = rowptr[n], r1 = rowptr[n + 1];
        if (r0 == r1) {
            if (lane < 32) { uint2 z; z.x = 0u; z.y = 0u; *(uint2*)(aggb + (size_t)n * 64 + lane * 2) = z; }
            continue;
        }
        float mm = -1e30f;
        for (int i = r0 + s32; i < r1; i += 32) mm = fmaxf(mm, evals[2 * i + hb]);
        mm = fmaxf(mm, __shfl_xor(mm, 1));
        mm = fmaxf(mm, __shfl_xor(mm, 2));
        mm = fmaxf(mm, __shfl_xor(mm, 4));
        mm = fmaxf(mm, __shfl_xor(mm, 8));
        mm = fmaxf(mm, __shfl_xor(mm, 32));
        float z = 0.f;
        for (int i = r0 + s32; i < r1; i += 32) z += expf(evals[2 * i + hb] - mm);
        z += __shfl_xor(z, 1);
        z += __shfl_xor(z, 2);
        z += __shfl_xor(z, 4);
        z += __shfl_xor(z, 8);
        z += __shfl_xor(z, 32);
        float rz = 1.f / z;
        float acc0 = 0.f, acc1 = 0.f, acc2 = 0.f, acc3 = 0.f;
        for (int i = r0; i < r1; i += 8) {
            uint2 cc[4]; float ww[4];
#pragma unroll
            for (int p = 0; p < 4; p++) {
                int ej = i + 2 * p + esel;
                bool v = ej < r1;
                int es = v ? ej : r0;
                cc[p] = *(const uint2*)(s + (size_t)src_s[es] * 384 + 256 + dsel);
                ww[p] = v ? expf(evals[2 * ej + hb] - mm) * rz : 0.f;
            }
#pragma unroll
            for (int p = 0; p < 4; p++) {
                acc0 = fmaf(ww[p], bfl(cc[p].x), acc0);
                acc1 = fmaf(ww[p], bfh(cc[p].x), acc1);
                acc2 = fmaf(ww[p], bfl(cc[p].y), acc2);
                acc3 = fmaf(ww[p], bfh(cc[p].y), acc3);
            }
        }
        acc0 += __shfl_xor(acc0, 32);
        acc1 += __shfl_xor(acc1, 32);
        acc2 += __shfl_xor(acc2, 32);
        acc3 += __shfl_xor(acc3, 32);
        if (lane < 32) {
            uint2 o;
            o.x = (unsigned)f2bf(acc0) | ((unsigned)f2bf(acc1) << 16);
            o.y = (unsigned)f2bf(acc2) | ((unsigned)f2bf(acc3) << 16);
            *(uint2*)(aggb + (size_t)n * 64 + lane * 2) = o;
        }
    }
}

// ---------------- node MLP + residual, MFMA: h' = gelu(agg@W1+b1)@W2+b2 + h ----------------
__global__ __launch_bounds__(256) void k_mlp(
    const bf16_t* __restrict__ aggb, const bf16_t* __restrict__ W1T, const float* __restrict__ b1,
    const bf16_t* __restrict__ W2T, const float* __restrict__ b2,
    const float* __restrict__ hin, float* __restrict__ hout, bf16_t* __restrict__ houtb,
    float* __restrict__ out, int col0)
{
    __shared__ __align__(16) bf16_t aggS[32 * 136];
    __shared__ __align__(16) bf16_t hidS[32 * 136];
    const int t = threadIdx.x;
    const int wave = t >> 6, lane = t & 63, l16 = lane & 15, quad = lane >> 4;
    const int n0 = blockIdx.x * 32;
    {   // stage agg tile: 32 rows x 256B (32B per thread)
        int r = t >> 3, sg = t & 7;
        *(s16x8*)(aggS + r * 136 + sg * 16) =
            *(const s16x8*)(aggb + (size_t)(n0 + r) * 128 + sg * 16);
        *(s16x8*)(aggS + r * 136 + sg * 16 + 8) =
            *(const s16x8*)(aggb + (size_t)(n0 + r) * 128 + sg * 16 + 8);
    }
    __syncthreads();
    const int ng = wave & 1, nh = wave >> 1;
    const int node = n0 + ng * 16 + l16;
    {   // GEMM1 + gelu -> hidS
        const bf16_t* brow = aggS + (ng * 16 + l16) * 136 + quad * 8;
        s16x8 B[4];
#pragma unroll
        for (int ks = 0; ks < 4; ks++) B[ks] = *(const s16x8*)(brow + ks * 32);
#pragma unroll
        for (int nt = 0; nt < 4; nt++) {
            int nb = nh * 64 + nt * 16;
            f32x4 acc = {0.f, 0.f, 0.f, 0.f};
#pragma unroll
            for (int ks = 0; ks < 4; ks++) {
                const s16x8 A = *(const s16x8*)(W1T + (size_t)(nb + l16) * 128 + ks * 32 + quad * 8);
                acc = __builtin_amdgcn_mfma_f32_16x16x32_bf16(A, B[ks], acc, 0, 0, 0);
            }
            const float4 bv = *(const float4*)(b1 + nb + quad * 4);
            ushort4 o;
            o.x = f2bf(gelu_f(acc[0] + bv.x));
            o.y = f2bf(gelu_f(acc[1] + bv.y));
            o.z = f2bf(gelu_f(acc[2] + bv.z));
            o.w = f2bf(gelu_f(acc[3] + bv.w));
            *(ushort4*)(hidS + (ng * 16 + l16) * 136 + nb + quad * 4) = o;
        }
    }
    __syncthreads();
    {   // GEMM2 + bias + residual -> hout/houtb/out
        const int jh = wave >> 1;
        const bf16_t* hrow = hidS + (ng * 16 + l16) * 136 + quad * 8;
        s16x8 H[4];
#pragma unroll
        for (int ks = 0; ks < 4; ks++) H[ks] = *(const s16x8*)(hrow + ks * 32);
#pragma unroll
        for (int jt = 0; jt < 2; jt++) {
            int jb = jh * 32 + jt * 16;
            f32x4 acc = {0.f, 0.f, 0.f, 0.f};
#pragma unroll
            for (int ks = 0; ks < 4; ks++) {
                const s16x8 A = *(const s16x8*)(W2T + (size_t)(jb + l16) * 128 + ks * 32 + quad * 8);
                acc = __builtin_amdgcn_mfma_f32_16x16x32_bf16(A, H[ks], acc, 0, 0, 0);
            }
            int j0 = jb + quad * 4;
            const float4 bv = *(const float4*)(b2 + j0);
            const float4 hv = *(const float4*)(hin + (size_t)node * 64 + j0);
            float4 v;
            v.x = acc[0] + bv.x + hv.x;
            v.y = acc[1] + bv.y + hv.y;
            v.z = acc[2] + bv.z + hv.z;
            v.w = acc[3] + bv.w + hv.w;
            *(float4*)(hout + (size_t)node * 64 + j0) = v;
            ushort4 ob;
            ob.x = f2bf(v.x); ob.y = f2bf(v.y); ob.z = f2bf(v.z); ob.w = f2bf(v.w);
            *(ushort4*)(houtb + (size_t)node * 64 + j0) = ob;
            if (node < N_NODES)
                *(float4*)(out + (size_t)node * 704 + col0 + j0) = v;
        }
    }
}

// ---------------- graph max pooling over node_emb cols 0..351 ----------------
__device__ __forceinline__ unsigned fmap(float v) {
    unsigned u = __float_as_uint(v);
    return (u & 0x80000000u) ? ~u : (u | 0x80000000u);
}

__global__ __launch_bounds__(384) void k_colmax(const float* __restrict__ out, unsigned* __restrict__ gmax) {
    int c = threadIdx.x;
    if (c >= 352) return;
    float m = -1e30f;
    for (int n = blockIdx.x; n < N_NODES; n += gridDim.x)
        m = fmaxf(m, out[(size_t)n * 704 + c]);
    atomicMax(gmax + c, fmap(m));
}

__global__ __launch_bounds__(384) void k_bcast(const unsigned* __restrict__ gmax, float* __restrict__ out) {
    int c = threadIdx.x;
    if (c >= 352) return;
    unsigned u = gmax[c];
    u = (u & 0x80000000u) ? (u ^ 0x80000000u) : ~u;
    float v = __uint_as_float(u);
    for (int n = blockIdx.x; n < N_NODES; n += gridDim.x)
        out[(size_t)n * 704 + 352 + c] = v;
}

// ---------------- host launcher ----------------
extern "C" void kernel_launch(void* const* d_in, const int* in_sizes, int n_in,
                              void* d_out, int out_size, void* d_ws, size_t ws_size,
                              hipStream_t stream)
{
    (void)in_sizes; (void)n_in; (void)out_size; (void)ws_size;
    const float* feat     = (const float*)d_in[0];
    const float* att_rc   = (const float*)d_in[1];
    const float* att_rp   = (const float*)d_in[2];
    const float* type_emb = (const float*)d_in[3];
    const float* rid_emb  = (const float*)d_in[4];
    const float* rc_W     = (const float*)d_in[5];
    const float* rc_b     = (const float*)d_in[6];
    const float* rp_W     = (const float*)d_in[7];
    const float* rp_b     = (const float*)d_in[8];
    const float* fe_W1    = (const float*)d_in[9];
    const float* fe_b1    = (const float*)d_in[10];
    const float* fe_W2    = (const float*)d_in[11];
    const float* fe_b2    = (const float*)d_in[12];
    const float* W_ni     = (const float*)d_in[13];
    const float* W_nj     = (const float*)d_in[14];
    const float* W_fij    = (const float*)d_in[15];
    const float* W_node   = (const float*)d_in[16];
    const float* b_node   = (const float*)d_in[17];
    const float* attn     = (const float*)d_in[18];
    const float* mlp_W1   = (const float*)d_in[19];
    const float* mlp_b1   = (const float*)d_in[20];
    const float* mlp_W2   = (const float*)d_in[21];
    const float* mlp_b2   = (const float*)d_in[22];
    const int* src   = (const int*)d_in[23];
    const int* dst   = (const int*)d_in[24];
    const int* etype = (const int*)d_in[25];
    const int* erid  = (const int*)d_in[26];
    float* out = (float*)d_out;

    // Workspace layout (byte cursor, all chunks 16B aligned).
    char* cur = (char*)d_ws;
    auto alloc = [&](size_t bytes) { char* p = cur; cur += (bytes + 15) & ~(size_t)15; return p; };
    float* h_a    = (float*)alloc((size_t)NPAD * 64 * 4);
    float* h_b    = (float*)alloc((size_t)NPAD * 64 * 4);
    bf16_t* hb_a  = (bf16_t*)alloc((size_t)NPAD * 64 * 2);
    bf16_t* hb_b  = (bf16_t*)alloc((size_t)NPAD * 64 * 2);
    bf16_t* s     = (bf16_t*)alloc((size_t)NPAD * 384 * 2);
    float* ev     = (float*)alloc((size_t)N_EDGES * 2 * 4);
    bf16_t* aggb  = (bf16_t*)alloc((size_t)NPAD * 128 * 2);
    int* deg     = (int*)alloc((size_t)N_NODES * 4);
    int* rowptr  = (int*)alloc((size_t)(N_NODES + 1) * 4);
    int* cursor  = (int*)alloc((size_t)N_NODES * 4);
    int* eidx    = (int*)alloc((size_t)N_EDGES * 4);
    int* src_s   = (int*)alloc((size_t)N_EDGES * 4);
    uint4* emA   = (uint4*)alloc((size_t)N_EDGES * 16);
    uint2* emB   = (uint2*)alloc((size_t)N_EDGES * 8);
    float* baseT = (float*)alloc((size_t)315 * 64 * 4);
    bf16_t* WT   = (bf16_t*)alloc((size_t)NLAYER * 128 * 64 * 2);
    bf16_t* W3T  = (bf16_t*)alloc((size_t)NLAYER * 384 * 64 * 2);
    bf16_t* W1T  = (bf16_t*)alloc((size_t)NLAYER * 128 * 128 * 2);
    bf16_t* W2T  = (bf16_t*)alloc((size_t)NLAYER * 64 * 128 * 2);
    int* bsum    = (int*)alloc(64 * 4);
    int* boff    = (int*)alloc(64 * 4);
    unsigned* gmax = (unsigned*)alloc(352 * 4);

    const int NB = (N_NODES + 1023) / 1024;  // 49

    k_zero32<<<(N_NODES + 255) / 256, 256, 0, stream>>>((unsigned*)deg, N_NODES);
    k_zero32<<<2, 256, 0, stream>>>(gmax, 352);
    k_hist<<<N_EDGES / 256, 256, 0, stream>>>(dst, deg);
    k_scan1<<<NB, 1024, 0, stream>>>(deg, rowptr, bsum);
    k_scan2<<<1, 64, 0, stream>>>(bsum, boff, NB);
    k_scan3<<<NB, 1024, 0, stream>>>(rowptr, boff);
    k_copy<<<(N_NODES + 255) / 256, 256, 0, stream>>>(rowptr, cursor);
    k_scatter<<<N_EDGES / 256, 256, 0, stream>>>(dst, cursor, eidx);
    k_sortgather<<<N_EDGES / 256, 256, 0, stream>>>(eidx, src, dst, etype, erid, att_rc, att_rp,
                                                    src_s, emA, emB);
    k_base<<<(315 * 64 + 255) / 256, 256, 0, stream>>>(type_emb, rid_emb, rc_b, rp_b, baseT);
    k_wprep<<<(NLAYER * 57344 + 255) / 256, 256, 0, stream>>>(
        W_fij, W_ni, W_nj, W_node, mlp_W1, mlp_W2, WT, W3T, W1T, W2T);
    k_fe<<<N_NODES / 4, 256, 0, stream>>>(feat, fe_W1, fe_b1, fe_W2, fe_b2, h_a, hb_a, out);

    float* hc = h_a;  bf16_t* hbc = hb_a;
    float* hn = h_b;  bf16_t* hbn = hb_b;
    for (int l = 0; l < NLAYER; l++) {
        k_node3<<<NPAD / 32, 256, 0, stream>>>(hbc, W3T + (size_t)l * 384 * 64, b_node + l * 128, s);
        k_edge<<<EDGE_BLOCKS, 256, 0, stream>>>(s, WT + l * 128 * 64, attn + l * 128,
                                                emA, emB, baseT, rc_W, rp_W, ev);
        k_soft_agg<<<4096, 256, 0, stream>>>(rowptr, src_s, ev, s, (unsigned*)aggb);
        k_mlp<<<NPAD / 32, 256, 0, stream>>>(aggb, W1T + (size_t)l * 128 * 128, mlp_b1 + l * 128,
                                             W2T + (size_t)l * 64 * 128, mlp_b2 + l * 64,
                                             hc, hn, hbn, out, 32 + 64 * (l + 1));
        float* tf = hc; hc = hn; hn = tf;
        bf16_t* tb = hbc; hbc = hbn; hbn = tb;
    }
    k_colmax<<<512, 384, 0, stream>>>(out, gmax);
    k_bcast<<<512, 384, 0, stream>>>(gmax, out);
}

// Round 6
// 1168.720 us; speedup vs baseline: 1.0818x; 1.0766x over previous
//
#include <hip/hip_runtime.h>
#include <math.h>

// Problem constants (fixed by the reference).
#define N_NODES 50000
#define N_EDGES 640000   // divisible by 32 (20000 tiles) and 256
#define NLAYER  4
#define NPAD    50016    // N_NODES rounded up to 32

typedef unsigned short bf16_t;
typedef __attribute__((ext_vector_type(8))) short s16x8;   // 8 bf16 = 4 VGPR (MFMA A/B frag)
typedef __attribute__((ext_vector_type(4))) float f32x4;   // MFMA C/D frag

__device__ __forceinline__ float gelu_f(float x) {
    return 0.5f * x * (1.0f + tanhf(0.7978845608028654f * (x + 0.044715f * x * x * x)));
}

__device__ __forceinline__ bf16_t f2bf(float f) {
    unsigned u = __float_as_uint(f);
    unsigned r = (u + 0x7FFFu + ((u >> 16) & 1u)) >> 16;   // RNE
    return (bf16_t)r;
}
__device__ __forceinline__ float bf2f(bf16_t h) { return __uint_as_float(((unsigned)h) << 16); }
__device__ __forceinline__ float bfl(unsigned x) { return __uint_as_float(x << 16); }
__device__ __forceinline__ float bfh(unsigned x) { return __uint_as_float(x & 0xFFFF0000u); }

// ---------------- CSR build (counting sort by dst) ----------------
__global__ void k_zero32(unsigned* p, int n) {
    int i = blockIdx.x * 256 + threadIdx.x;
    if (i < n) p[i] = 0u;
}

__global__ void k_hist(const int* __restrict__ dst, int* __restrict__ deg) {
    int i = blockIdx.x * 256 + threadIdx.x;
    if (i < N_EDGES) atomicAdd(&deg[dst[i]], 1);
}

__global__ void k_scan1(const int* __restrict__ deg, int* __restrict__ rowptr, int* __restrict__ bsum) {
    __shared__ int sd[1024];
    int gi = blockIdx.x * 1024 + threadIdx.x;
    int v = (gi < N_NODES) ? deg[gi] : 0;
    sd[threadIdx.x] = v;
    __syncthreads();
    for (int off = 1; off < 1024; off <<= 1) {
        int t2 = (threadIdx.x >= (unsigned)off) ? sd[threadIdx.x - off] : 0;
        __syncthreads();
        sd[threadIdx.x] += t2;
        __syncthreads();
    }
    if (gi < N_NODES) rowptr[gi] = sd[threadIdx.x] - v;  // block-local exclusive
    if (threadIdx.x == 1023) bsum[blockIdx.x] = sd[1023];
}

__global__ void k_scan2(const int* __restrict__ bsum, int* __restrict__ boff, int nb) {
    if (threadIdx.x == 0 && blockIdx.x == 0) {
        int run = 0;
        for (int b = 0; b < nb; b++) { boff[b] = run; run += bsum[b]; }
    }
}

__global__ void k_scan3(int* __restrict__ rowptr, const int* __restrict__ boff) {
    int gi = blockIdx.x * 1024 + threadIdx.x;
    if (gi < N_NODES) rowptr[gi] += boff[blockIdx.x];
    if (gi == 0) rowptr[N_NODES] = N_EDGES;
}

__global__ void k_copy(const int* __restrict__ a, int* __restrict__ b) {
    int i = blockIdx.x * 256 + threadIdx.x;
    if (i < N_NODES) b[i] = a[i];
}

__global__ void k_scatter(const int* __restrict__ dst, int* __restrict__ cursor, int* __restrict__ eidx) {
    int i = blockIdx.x * 256 + threadIdx.x;
    if (i < N_EDGES) {
        int p = atomicAdd(&cursor[dst[i]], 1);
        eidx[p] = i;
    }
}

// Gather per-edge fields into dst-sorted order, compact 24 B/edge:
// emA[i] = { src, dst, combo = etype*9+erid, rc0|rc1<<16 (bf16) }
// emB[i] = { rp0|rp1<<16 (bf16), rp2 (bf16) }
__global__ void k_sortgather(
    const int* __restrict__ eidx, const int* __restrict__ src, const int* __restrict__ dst,
    const int* __restrict__ etype, const int* __restrict__ erid,
    const float* __restrict__ att_rc, const float* __restrict__ att_rp,
    int* __restrict__ src_s, uint4* __restrict__ emA, uint2* __restrict__ emB)
{
    int i = blockIdx.x * 256 + threadIdx.x;
    if (i < N_EDGES) {
        int e = eidx[i];
        int sv = src[e];
        src_s[i] = sv;
        uint4 a;
        a.x = (unsigned)sv;
        a.y = (unsigned)dst[e];
        a.z = (unsigned)(etype[e] * 9 + erid[e]);
        a.w = (unsigned)f2bf(att_rc[2 * e]) | ((unsigned)f2bf(att_rc[2 * e + 1]) << 16);
        uint2 b;
        b.x = (unsigned)f2bf(att_rp[3 * e]) | ((unsigned)f2bf(att_rp[3 * e + 1]) << 16);
        b.y = (unsigned)f2bf(att_rp[3 * e + 2]);
        emA[i] = a;
        emB[i] = b;
    }
}

// ---------------- (etype,erid)-combo base table: 315 x 64 fp32 ----------
__global__ void k_base(const float* __restrict__ type_emb, const float* __restrict__ rid_emb,
                       const float* __restrict__ rcb, const float* __restrict__ rpb,
                       float* __restrict__ base)
{
    int idx = blockIdx.x * 256 + threadIdx.x;
    if (idx >= 315 * 64) return;
    int c = idx >> 6, k = idx & 63;
    int et = c / 9, er = c % 9;
    base[idx] = type_emb[et * 64 + k] + rid_emb[er * 64 + k] + rcb[k] + rpb[k];
}

// ---------------- rank-factorized edge projection tables (per layer, fp32) ----------
// baseW[l][c][n] = sum_k base[c][k] * Wfij[l][k][n]   (315 x 128 per layer, ~161 KB)
__global__ void k_basew(const float* __restrict__ base, const float* __restrict__ Wfij,
                        float* __restrict__ baseW)
{
    int idx = blockIdx.x * 256 + threadIdx.x;
    if (idx >= NLAYER * 315 * 128) return;
    int l = idx / (315 * 128), r = idx % (315 * 128);
    int c = r >> 7, n = r & 127;
    const float* bp = base + c * 64;
    const float* wp = Wfij + l * 8192 + n;
    float acc = 0.f;
#pragma unroll 8
    for (int k = 0; k < 64; k++) acc = fmaf(bp[k], wp[k * 128], acc);
    baseW[idx] = acc;
}

// CWf[l][j][n] = sum_k w_j[k] * Wfij[l][k][n], w_j = rcW rows (j<2) / rpW rows (j>=2)
__global__ void k_cw(const float* __restrict__ rcW, const float* __restrict__ rpW,
                     const float* __restrict__ Wfij, float* __restrict__ CWf)
{
    int idx = blockIdx.x * 256 + threadIdx.x;
    if (idx >= NLAYER * 5 * 128) return;
    int l = idx / 640, r = idx % 640;
    int j = r >> 7, n = r & 127;
    const float* cp = (j < 2) ? (rcW + j * 64) : (rpW + (j - 2) * 64);
    const float* wp = Wfij + l * 8192 + n;
    float acc = 0.f;
#pragma unroll 8
    for (int k = 0; k < 64; k++) acc = fmaf(cp[k], wp[k * 128], acc);
    CWf[idx] = acc;
}

// Weight transposes to bf16, k-contiguous rows (MFMA A-operand friendly).
__global__ void k_wprep(const float* __restrict__ Wfij, const float* __restrict__ Wni,
                        const float* __restrict__ Wnj, const float* __restrict__ Wnode,
                        const float* __restrict__ W1, const float* __restrict__ W2,
                        bf16_t* __restrict__ WT, bf16_t* __restrict__ W3T,
                        bf16_t* __restrict__ W1T, bf16_t* __restrict__ W2T)
{
    int idx = blockIdx.x * 256 + threadIdx.x;
    if (idx >= NLAYER * 57344) return;
    int l = idx / 57344, r = idx % 57344;
    if (r < 8192) {
        int n = r >> 6, k = r & 63;
        WT[l * 8192 + r] = f2bf(Wfij[l * 8192 + k * 128 + n]);
    } else if (r < 32768) {
        int q = r - 8192; int c = q >> 6, k = q & 63;
        const float* src = (c < 128) ? Wni : (c < 256) ? Wnj : Wnode;
        W3T[l * 24576 + q] = f2bf(src[l * 8192 + k * 128 + (c & 127)]);
    } else if (r < 49152) {
        int q = r - 32768; int n = q >> 7, k = q & 127;
        W1T[l * 16384 + q] = f2bf(W1[l * 16384 + k * 128 + n]);
    } else {
        int q = r - 49152; int j = q >> 7, k = q & 127;
        W2T[l * 8192 + q] = f2bf(W2[l * 8192 + k * 64 + j]);
    }
}

// ---------------- feature encoder: h0 = gelu(feat@W1+b1)@W2+b2 ----------------
__global__ __launch_bounds__(256) void k_fe(
    const float* __restrict__ feat, const float* __restrict__ W1, const float* __restrict__ b1,
    const float* __restrict__ W2, const float* __restrict__ b2,
    float* __restrict__ h, bf16_t* __restrict__ hb, float* __restrict__ out)
{
    __shared__ float hid[4][64];
    int w = threadIdx.x >> 6, lane = threadIdx.x & 63;
    int n = blockIdx.x * 4 + w;  // N divisible by 4
    float a = b1[lane];
#pragma unroll 8
    for (int k = 0; k < 32; k++) a = fmaf(feat[n * 32 + k], W1[k * 64 + lane], a);
    hid[w][lane] = gelu_f(a);
    __syncthreads();
    float o = b2[lane];
#pragma unroll 8
    for (int k = 0; k < 64; k++) o = fmaf(hid[w][k], W2[k * 64 + lane], o);
    h[n * 64 + lane] = o;
    hb[n * 64 + lane] = f2bf(o);
    out[n * 704 + 32 + lane] = o;
    if (lane < 32) out[n * 704 + lane] = feat[n * 32 + lane];
}

// ---------------- s = h @ [W_ni | W_nj | W_node(+b)] -> [NPAD,384] bf16, MFMA ----------------
__global__ __launch_bounds__(256) void k_node3(
    const bf16_t* __restrict__ hb, const bf16_t* __restrict__ W3T,
    const float* __restrict__ bnode, bf16_t* __restrict__ s)
{
    __shared__ __align__(16) bf16_t hbS[32 * 72];
    const int t = threadIdx.x;
    const int wave = t >> 6, lane = t & 63, l16 = lane & 15, quad = lane >> 4;
    const int n0 = blockIdx.x * 32;
    {   // stage hb tile: 32 rows x 128B
        int r = t >> 3, sg = t & 7;
        *(s16x8*)(hbS + r * 72 + sg * 8) = *(const s16x8*)(hb + (size_t)(n0 + r) * 64 + sg * 8);
    }
    __syncthreads();
    const int ng = wave & 1, ch = wave >> 1;
    const s16x8 B0 = *(const s16x8*)(hbS + (ng * 16 + l16) * 72 + quad * 8);
    const s16x8 B1 = *(const s16x8*)(hbS + (ng * 16 + l16) * 72 + 32 + quad * 8);
    const int node = n0 + ng * 16 + l16;
#pragma unroll
    for (int nt = 0; nt < 12; nt++) {
        int c0 = ch * 192 + nt * 16;
        const s16x8 A0 = *(const s16x8*)(W3T + (size_t)(c0 + l16) * 64 + quad * 8);
        const s16x8 A1 = *(const s16x8*)(W3T + (size_t)(c0 + l16) * 64 + 32 + quad * 8);
        f32x4 acc = {0.f, 0.f, 0.f, 0.f};
        acc = __builtin_amdgcn_mfma_f32_16x16x32_bf16(A0, B0, acc, 0, 0, 0);
        acc = __builtin_amdgcn_mfma_f32_16x16x32_bf16(A1, B1, acc, 0, 0, 0);
        int cb = c0 + quad * 4;
        float4 bv = make_float4(0.f, 0.f, 0.f, 0.f);
        if (cb >= 256) bv = *(const float4*)(bnode + cb - 256);
        ushort4 o;
        o.x = f2bf(acc[0] + bv.x);
        o.y = f2bf(acc[1] + bv.y);
        o.z = f2bf(acc[2] + bv.z);
        o.w = f2bf(acc[3] + bv.w);
        *(ushort4*)(s + (size_t)node * 384 + cb) = o;
    }
}

// ---------------- fused edge kernel: pure VALU, one edge per thread ----------------
// fedge[n] = baseW[combo][n] + sum_j R_j * CW[j][n]  (rank-5 factorization of ef@W_fij,
// exact by linearity; fp32 throughout -> closer to the fp32 reference than the old
// bf16-MFMA path). Then e[h] = sum_d leaky(fedge[h*64+d] + sni[d] + snj[d]) * attn[h*64+d]
// -- the exact consumed-dim pairing of the harness-verified R0/R3/R4/R5 kernels.
// No MFMA, no LDS, no barriers: CW/attn are wave-uniform reads (scalarized), only the
// s-row and baseW-row gathers hit the vector memory pipe. ~70 VGPR -> high occupancy.
__global__ __launch_bounds__(256) void k_edge(
    const bf16_t* __restrict__ s, const float* __restrict__ baseW,
    const float* __restrict__ CWf, const float* __restrict__ attn,
    const uint4* __restrict__ emA, const uint2* __restrict__ emB,
    float* __restrict__ evals)
{
    const int i = blockIdx.x * 256 + threadIdx.x;   // grid covers N_EDGES exactly
    const uint4 ma = emA[i];
    const uint2 mb = emB[i];
    const bf16_t* sr = s + (size_t)ma.x * 384;          // sni dims 0..63
    const bf16_t* dr = s + (size_t)ma.y * 384 + 128;    // snj dims 0..63
    const float* bw = baseW + (size_t)ma.z * 128;
    const float r0 = bfl(ma.w), r1 = bfh(ma.w);
    const float r2 = bfl(mb.x), r3 = bfh(mb.x), r4 = bfl(mb.y);

    float e[2] = {0.f, 0.f};
#pragma unroll
    for (int c = 0; c < 4; c++) {
        const int d0 = c * 16;
        const uint4 u0 = *(const uint4*)(sr + d0);
        const uint4 u1 = *(const uint4*)(sr + d0 + 8);
        const uint4 v0 = *(const uint4*)(dr + d0);
        const uint4 v1 = *(const uint4*)(dr + d0 + 8);
        float snd[16];
        snd[0]  = bfl(u0.x) + bfl(v0.x);  snd[1]  = bfh(u0.x) + bfh(v0.x);
        snd[2]  = bfl(u0.y) + bfl(v0.y);  snd[3]  = bfh(u0.y) + bfh(v0.y);
        snd[4]  = bfl(u0.z) + bfl(v0.z);  snd[5]  = bfh(u0.z) + bfh(v0.z);
        snd[6]  = bfl(u0.w) + bfl(v0.w);  snd[7]  = bfh(u0.w) + bfh(v0.w);
        snd[8]  = bfl(u1.x) + bfl(v1.x);  snd[9]  = bfh(u1.x) + bfh(v1.x);
        snd[10] = bfl(u1.y) + bfl(v1.y);  snd[11] = bfh(u1.y) + bfh(v1.y);
        snd[12] = bfl(u1.z) + bfl(v1.z);  snd[13] = bfh(u1.z) + bfh(v1.z);
        snd[14] = bfl(u1.w) + bfl(v1.w);  snd[15] = bfh(u1.w) + bfh(v1.w);
#pragma unroll
        for (int h = 0; h < 2; h++) {
#pragma unroll
            for (int q = 0; q < 4; q++) {
                const int n = h * 64 + d0 + q * 4;
                const float4 b  = *(const float4*)(bw + n);
                const float4 w0 = *(const float4*)(CWf + n);
                const float4 w1 = *(const float4*)(CWf + 128 + n);
                const float4 w2 = *(const float4*)(CWf + 256 + n);
                const float4 w3 = *(const float4*)(CWf + 384 + n);
                const float4 w4 = *(const float4*)(CWf + 512 + n);
                const float4 at = *(const float4*)(attn + n);
                float f0 = b.x, f1 = b.y, f2 = b.z, f3 = b.w;
                f0 = fmaf(r0, w0.x, f0); f1 = fmaf(r0, w0.y, f1); f2 = fmaf(r0, w0.z, f2); f3 = fmaf(r0, w0.w, f3);
                f0 = fmaf(r1, w1.x, f0); f1 = fmaf(r1, w1.y, f1); f2 = fmaf(r1, w1.z, f2); f3 = fmaf(r1, w1.w, f3);
                f0 = fmaf(r2, w2.x, f0); f1 = fmaf(r2, w2.y, f1); f2 = fmaf(r2, w2.z, f2); f3 = fmaf(r2, w2.w, f3);
                f0 = fmaf(r3, w3.x, f0); f1 = fmaf(r3, w3.y, f1); f2 = fmaf(r3, w3.z, f2); f3 = fmaf(r3, w3.w, f3);
                f0 = fmaf(r4, w4.x, f0); f1 = fmaf(r4, w4.y, f1); f2 = fmaf(r4, w4.z, f2); f3 = fmaf(r4, w4.w, f3);
                f0 += snd[q * 4 + 0];
                f1 += snd[q * 4 + 1];
                f2 += snd[q * 4 + 2];
                f3 += snd[q * 4 + 3];
                f0 = (f0 >= 0.f) ? f0 : 0.2f * f0;
                f1 = (f1 >= 0.f) ? f1 : 0.2f * f1;
                f2 = (f2 >= 0.f) ? f2 : 0.2f * f2;
                f3 = (f3 >= 0.f) ? f3 : 0.2f * f3;
                e[h] = fmaf(f0, at.x, e[h]);
                e[h] = fmaf(f1, at.y, e[h]);
                e[h] = fmaf(f2, at.z, e[h]);
                e[h] = fmaf(f3, at.w, e[h]);
            }
        }
    }
    float2 ev2;
    ev2.x = e[0];
    ev2.y = e[1];
    *(float2*)(evals + 2 * (size_t)i) = ev2;
}

// ---------------- per-dst softmax + aggregation -> aggb bf16 ----------------
// Paired-edge gather: lanes 0-31 even edges, 32-63 odd edges; lane owns 4 dims (8 B load).
// Per-head stats in 32-lane head-groups (bit4 = head) via shfl_xor {1,2,4,8,32}.
__global__ __launch_bounds__(256) void k_soft_agg(
    const int* __restrict__ rowptr, const int* __restrict__ src_s,
    const float* __restrict__ evals, const bf16_t* __restrict__ s,
    unsigned* __restrict__ aggb)   // [NPAD][64] uints = [NPAD][128] bf16
{
    int lane = threadIdx.x & 63;
    int wid = (blockIdx.x * 256 + threadIdx.x) >> 6;
    int nw = (gridDim.x * 256) >> 6;
    const int hb = (lane >> 4) & 1;                    // head for this lane's dims
    const int esel = lane >> 5;                        // 0: even edge of pair, 1: odd
    const int s32 = (lane & 15) | ((lane >> 5) << 4);  // 0..31 within head-group
    const int dsel = (lane & 31) * 4;                  // 4 bf16 dims per lane
    for (int n = wid; n < N_NODES; n += nw) {
        int r0 = rowptr[n], r1 = rowptr[n + 1];
        if (r0 == r1) {
            if (lane < 32) { uint2 z; z.x = 0u; z.y = 0u; *(uint2*)(aggb + (size_t)n * 64 + lane * 2) = z; }
            continue;
        }
        float mm = -1e30f;
        for (int i = r0 + s32; i < r1; i += 32) mm = fmaxf(mm, evals[2 * i + hb]);
        mm = fmaxf(mm, __shfl_xor(mm, 1));
        mm = fmaxf(mm, __shfl_xor(mm, 2));
        mm = fmaxf(mm, __shfl_xor(mm, 4));
        mm = fmaxf(mm, __shfl_xor(mm, 8));
        mm = fmaxf(mm, __shfl_xor(mm, 32));
        float z = 0.f;
        for (int i = r0 + s32; i < r1; i += 32) z += expf(evals[2 * i + hb] - mm);
        z += __shfl_xor(z, 1);
        z += __shfl_xor(z, 2);
        z += __shfl_xor(z, 4);
        z += __shfl_xor(z, 8);
        z += __shfl_xor(z, 32);
        float rz = 1.f / z;
        float acc0 = 0.f, acc1 = 0.f, acc2 = 0.f, acc3 = 0.f;
        for (int i = r0; i < r1; i += 8) {
            uint2 cc[4]; float ww[4];
#pragma unroll
            for (int p = 0; p < 4; p++) {
                int ej = i + 2 * p + esel;
                bool v = ej < r1;
                int es = v ? ej : r0;
                cc[p] = *(const uint2*)(s + (size_t)src_s[es] * 384 + 256 + dsel);
                ww[p] = v ? expf(evals[2 * ej + hb] - mm) * rz : 0.f;
            }
#pragma unroll
            for (int p = 0; p < 4; p++) {
                acc0 = fmaf(ww[p], bfl(cc[p].x), acc0);
                acc1 = fmaf(ww[p], bfh(cc[p].x), acc1);
                acc2 = fmaf(ww[p], bfl(cc[p].y), acc2);
                acc3 = fmaf(ww[p], bfh(cc[p].y), acc3);
            }
        }
        acc0 += __shfl_xor(acc0, 32);
        acc1 += __shfl_xor(acc1, 32);
        acc2 += __shfl_xor(acc2, 32);
        acc3 += __shfl_xor(acc3, 32);
        if (lane < 32) {
            uint2 o;
            o.x = (unsigned)f2bf(acc0) | ((unsigned)f2bf(acc1) << 16);
            o.y = (unsigned)f2bf(acc2) | ((unsigned)f2bf(acc3) << 16);
            *(uint2*)(aggb + (size_t)n * 64 + lane * 2) = o;
        }
    }
}

// ---------------- node MLP + residual, MFMA: h' = gelu(agg@W1+b1)@W2+b2 + h ----------------
__global__ __launch_bounds__(256) void k_mlp(
    const bf16_t* __restrict__ aggb, const bf16_t* __restrict__ W1T, const float* __restrict__ b1,
    const bf16_t* __restrict__ W2T, const float* __restrict__ b2,
    const float* __restrict__ hin, float* __restrict__ hout, bf16_t* __restrict__ houtb,
    float* __restrict__ out, int col0)
{
    __shared__ __align__(16) bf16_t aggS[32 * 136];
    __shared__ __align__(16) bf16_t hidS[32 * 136];
    const int t = threadIdx.x;
    const int wave = t >> 6, lane = t & 63, l16 = lane & 15, quad = lane >> 4;
    const int n0 = blockIdx.x * 32;
    {   // stage agg tile: 32 rows x 256B (32B per thread)
        int r = t >> 3, sg = t & 7;
        *(s16x8*)(aggS + r * 136 + sg * 16) =
            *(const s16x8*)(aggb + (size_t)(n0 + r) * 128 + sg * 16);
        *(s16x8*)(aggS + r * 136 + sg * 16 + 8) =
            *(const s16x8*)(aggb + (size_t)(n0 + r) * 128 + sg * 16 + 8);
    }
    __syncthreads();
    const int ng = wave & 1, nh = wave >> 1;
    const int node = n0 + ng * 16 + l16;
    {   // GEMM1 + gelu -> hidS
        const bf16_t* brow = aggS + (ng * 16 + l16) * 136 + quad * 8;
        s16x8 B[4];
#pragma unroll
        for (int ks = 0; ks < 4; ks++) B[ks] = *(const s16x8*)(brow + ks * 32);
#pragma unroll
        for (int nt = 0; nt < 4; nt++) {
            int nb = nh * 64 + nt * 16;
            f32x4 acc = {0.f, 0.f, 0.f, 0.f};
#pragma unroll
            for (int ks = 0; ks < 4; ks++) {
                const s16x8 A = *(const s16x8*)(W1T + (size_t)(nb + l16) * 128 + ks * 32 + quad * 8);
                acc = __builtin_amdgcn_mfma_f32_16x16x32_bf16(A, B[ks], acc, 0, 0, 0);
            }
            const float4 bv = *(const float4*)(b1 + nb + quad * 4);
            ushort4 o;
            o.x = f2bf(gelu_f(acc[0] + bv.x));
            o.y = f2bf(gelu_f(acc[1] + bv.y));
            o.z = f2bf(gelu_f(acc[2] + bv.z));
            o.w = f2bf(gelu_f(acc[3] + bv.w));
            *(ushort4*)(hidS + (ng * 16 + l16) * 136 + nb + quad * 4) = o;
        }
    }
    __syncthreads();
    {   // GEMM2 + bias + residual -> hout/houtb/out
        const int jh = wave >> 1;
        const bf16_t* hrow = hidS + (ng * 16 + l16) * 136 + quad * 8;
        s16x8 H[4];
#pragma unroll
        for (int ks = 0; ks < 4; ks++) H[ks] = *(const s16x8*)(hrow + ks * 32);
#pragma unroll
        for (int jt = 0; jt < 2; jt++) {
            int jb = jh * 32 + jt * 16;
            f32x4 acc = {0.f, 0.f, 0.f, 0.f};
#pragma unroll
            for (int ks = 0; ks < 4; ks++) {
                const s16x8 A = *(const s16x8*)(W2T + (size_t)(jb + l16) * 128 + ks * 32 + quad * 8);
                acc = __builtin_amdgcn_mfma_f32_16x16x32_bf16(A, H[ks], acc, 0, 0, 0);
            }
            int j0 = jb + quad * 4;
            const float4 bv = *(const float4*)(b2 + j0);
            const float4 hv = *(const float4*)(hin + (size_t)node * 64 + j0);
            float4 v;
            v.x = acc[0] + bv.x + hv.x;
            v.y = acc[1] + bv.y + hv.y;
            v.z = acc[2] + bv.z + hv.z;
            v.w = acc[3] + bv.w + hv.w;
            *(float4*)(hout + (size_t)node * 64 + j0) = v;
            ushort4 ob;
            ob.x = f2bf(v.x); ob.y = f2bf(v.y); ob.z = f2bf(v.z); ob.w = f2bf(v.w);
            *(ushort4*)(houtb + (size_t)node * 64 + j0) = ob;
            if (node < N_NODES)
                *(float4*)(out + (size_t)node * 704 + col0 + j0) = v;
        }
    }
}

// ---------------- graph max pooling over node_emb cols 0..351 ----------------
__device__ __forceinline__ unsigned fmap(float v) {
    unsigned u = __float_as_uint(v);
    return (u & 0x80000000u) ? ~u : (u | 0x80000000u);
}

__global__ __launch_bounds__(384) void k_colmax(const float* __restrict__ out, unsigned* __restrict__ gmax) {
    int c = threadIdx.x;
    if (c >= 352) return;
    float m = -1e30f;
    for (int n = blockIdx.x; n < N_NODES; n += gridDim.x)
        m = fmaxf(m, out[(size_t)n * 704 + c]);
    atomicMax(gmax + c, fmap(m));
}

__global__ __launch_bounds__(384) void k_bcast(const unsigned* __restrict__ gmax, float* __restrict__ out) {
    int c = threadIdx.x;
    if (c >= 352) return;
    unsigned u = gmax[c];
    u = (u & 0x80000000u) ? (u ^ 0x80000000u) : ~u;
    float v = __uint_as_float(u);
    for (int n = blockIdx.x; n < N_NODES; n += gridDim.x)
        out[(size_t)n * 704 + 352 + c] = v;
}

// ---------------- host launcher ----------------
extern "C" void kernel_launch(void* const* d_in, const int* in_sizes, int n_in,
                              void* d_out, int out_size, void* d_ws, size_t ws_size,
                              hipStream_t stream)
{
    (void)in_sizes; (void)n_in; (void)out_size; (void)ws_size;
    const float* feat     = (const float*)d_in[0];
    const float* att_rc   = (const float*)d_in[1];
    const float* att_rp   = (const float*)d_in[2];
    const float* type_emb = (const float*)d_in[3];
    const float* rid_emb  = (const float*)d_in[4];
    const float* rc_W     = (const float*)d_in[5];
    const float* rc_b     = (const float*)d_in[6];
    const float* rp_W     = (const float*)d_in[7];
    const float* rp_b     = (const float*)d_in[8];
    const float* fe_W1    = (const float*)d_in[9];
    const float* fe_b1    = (const float*)d_in[10];
    const float* fe_W2    = (const float*)d_in[11];
    const float* fe_b2    = (const float*)d_in[12];
    const float* W_ni     = (const float*)d_in[13];
    const float* W_nj     = (const float*)d_in[14];
    const float* W_fij    = (const float*)d_in[15];
    const float* W_node   = (const float*)d_in[16];
    const float* b_node   = (const float*)d_in[17];
    const float* attn     = (const float*)d_in[18];
    const float* mlp_W1   = (const float*)d_in[19];
    const float* mlp_b1   = (const float*)d_in[20];
    const float* mlp_W2   = (const float*)d_in[21];
    const float* mlp_b2   = (const float*)d_in[22];
    const int* src   = (const int*)d_in[23];
    const int* dst   = (const int*)d_in[24];
    const int* etype = (const int*)d_in[25];
    const int* erid  = (const int*)d_in[26];
    float* out = (float*)d_out;

    // Workspace layout (byte cursor, all chunks 16B aligned).
    char* cur = (char*)d_ws;
    auto alloc = [&](size_t bytes) { char* p = cur; cur += (bytes + 15) & ~(size_t)15; return p; };
    float* h_a    = (float*)alloc((size_t)NPAD * 64 * 4);
    float* h_b    = (float*)alloc((size_t)NPAD * 64 * 4);
    bf16_t* hb_a  = (bf16_t*)alloc((size_t)NPAD * 64 * 2);
    bf16_t* hb_b  = (bf16_t*)alloc((size_t)NPAD * 64 * 2);
    bf16_t* s     = (bf16_t*)alloc((size_t)NPAD * 384 * 2);
    float* ev     = (float*)alloc((size_t)N_EDGES * 2 * 4);
    bf16_t* aggb  = (bf16_t*)alloc((size_t)NPAD * 128 * 2);
    int* deg     = (int*)alloc((size_t)N_NODES * 4);
    int* rowptr  = (int*)alloc((size_t)(N_NODES + 1) * 4);
    int* cursor  = (int*)alloc((size_t)N_NODES * 4);
    int* eidx    = (int*)alloc((size_t)N_EDGES * 4);
    int* src_s   = (int*)alloc((size_t)N_EDGES * 4);
    uint4* emA   = (uint4*)alloc((size_t)N_EDGES * 16);
    uint2* emB   = (uint2*)alloc((size_t)N_EDGES * 8);
    float* baseT = (float*)alloc((size_t)315 * 64 * 4);
    float* baseW = (float*)alloc((size_t)NLAYER * 315 * 128 * 4);
    float* CWf   = (float*)alloc((size_t)NLAYER * 5 * 128 * 4);
    bf16_t* WT   = (bf16_t*)alloc((size_t)NLAYER * 128 * 64 * 2);
    bf16_t* W3T  = (bf16_t*)alloc((size_t)NLAYER * 384 * 64 * 2);
    bf16_t* W1T  = (bf16_t*)alloc((size_t)NLAYER * 128 * 128 * 2);
    bf16_t* W2T  = (bf16_t*)alloc((size_t)NLAYER * 64 * 128 * 2);
    int* bsum    = (int*)alloc(64 * 4);
    int* boff    = (int*)alloc(64 * 4);
    unsigned* gmax = (unsigned*)alloc(352 * 4);

    const int NB = (N_NODES + 1023) / 1024;  // 49

    k_zero32<<<(N_NODES + 255) / 256, 256, 0, stream>>>((unsigned*)deg, N_NODES);
    k_zero32<<<2, 256, 0, stream>>>(gmax, 352);
    k_hist<<<N_EDGES / 256, 256, 0, stream>>>(dst, deg);
    k_scan1<<<NB, 1024, 0, stream>>>(deg, rowptr, bsum);
    k_scan2<<<1, 64, 0, stream>>>(bsum, boff, NB);
    k_scan3<<<NB, 1024, 0, stream>>>(rowptr, boff);
    k_copy<<<(N_NODES + 255) / 256, 256, 0, stream>>>(rowptr, cursor);
    k_scatter<<<N_EDGES / 256, 256, 0, stream>>>(dst, cursor, eidx);
    k_sortgather<<<N_EDGES / 256, 256, 0, stream>>>(eidx, src, dst, etype, erid, att_rc, att_rp,
                                                    src_s, emA, emB);
    k_base<<<(315 * 64 + 255) / 256, 256, 0, stream>>>(type_emb, rid_emb, rc_b, rp_b, baseT);
    k_basew<<<(NLAYER * 315 * 128 + 255) / 256, 256, 0, stream>>>(baseT, W_fij, baseW);
    k_cw<<<(NLAYER * 5 * 128 + 255) / 256, 256, 0, stream>>>(rc_W, rp_W, W_fij, CWf);
    k_wprep<<<(NLAYER * 57344 + 255) / 256, 256, 0, stream>>>(
        W_fij, W_ni, W_nj, W_node, mlp_W1, mlp_W2, WT, W3T, W1T, W2T);
    k_fe<<<N_NODES / 4, 256, 0, stream>>>(feat, fe_W1, fe_b1, fe_W2, fe_b2, h_a, hb_a, out);

    float* hc = h_a;  bf16_t* hbc = hb_a;
    float* hn = h_b;  bf16_t* hbn = hb_b;
    for (int l = 0; l < NLAYER; l++) {
        k_node3<<<NPAD / 32, 256, 0, stream>>>(hbc, W3T + (size_t)l * 384 * 64, b_node + l * 128, s);
        k_edge<<<N_EDGES / 256, 256, 0, stream>>>(s, baseW + (size_t)l * 315 * 128,
                                                  CWf + (size_t)l * 640, attn + l * 128,
                                                  emA, emB, ev);
        k_soft_agg<<<4096, 256, 0, stream>>>(rowptr, src_s, ev, s, (unsigned*)aggb);
        k_mlp<<<NPAD / 32, 256, 0, stream>>>(aggb, W1T + (size_t)l * 128 * 128, mlp_b1 + l * 128,
                                             W2T + (size_t)l * 64 * 128, mlp_b2 + l * 64,
                                             hc, hn, hbn, out, 32 + 64 * (l + 1));
        float* tf = hc; hc = hn; hn = tf;
        bf16_t* tb = hbc; hbc = hbn; hbn = tb;
    }
    k_colmax<<<512, 384, 0, stream>>>(out, gmax);
    k_bcast<<<512, 384, 0, stream>>>(gmax, out);
}